// Round 3
// baseline (164.742 us; speedup 1.0000x reference)
//
#include <hip/hip_runtime.h>

#define N 512
#define U_CNT 128
#define F_STRIDE 80
#define FUF 64
#define TOPK 10
// log2(e)/tau with tau = 0.1
#define L2T 14.426950408889634f
#define LOG2E 1.4426950408889634f

#if defined(__has_builtin)
#if __has_builtin(__builtin_amdgcn_exp2f)
#define EXP2F(x) __builtin_amdgcn_exp2f(x)
#endif
#if __has_builtin(__builtin_amdgcn_logf)
#define LOG2F(x) __builtin_amdgcn_logf(x)
#endif
#endif
#ifndef EXP2F
#define EXP2F(x) exp2f(x)
#endif
#ifndef LOG2F
#define LOG2F(x) log2f(x)
#endif

__device__ __forceinline__ float block_reduce_sum(float v, float* buf) {
#pragma unroll
  for (int m = 32; m >= 1; m >>= 1) v += __shfl_xor(v, m, 64);
  __syncthreads();
  if ((threadIdx.x & 63) == 0) buf[threadIdx.x >> 6] = v;
  __syncthreads();
  float r = buf[0];
#pragma unroll
  for (int w2 = 1; w2 < 8; w2++) r += buf[w2];
  return r;
}

// One block per (user, which): which==0 -> ndcg outputs, which==1 -> diversity.
// p_sort is never materialized: p[i][j] = exp2(v_i*qs_j + rL_i + u_j) with
// qs_j = s_j*log2e/tau, u_j = cL_j - a_sum_j*log2e/tau (col log-factor),
// rL_i = row log-factor (init: -rowmax - log2(Z_i), then Sinkhorn updates).
__global__ __launch_bounds__(512) void loss_kernel(
    const float* __restrict__ batch, const float* __restrict__ sdiv,
    const float* __restrict__ sndcg, const float* __restrict__ rel,
    float* __restrict__ out) {
  __shared__ __align__(16) float sh_s[N];
  __shared__ __align__(16) float sh_qs[N];
  __shared__ __align__(16) float sh_u[N];
  __shared__ __align__(16) float sh_rL[N];
  __shared__ __align__(16) float sh_aux[N];  // rel (ndcg) | approx_rank sigmoid (div)
  __shared__ __align__(16) float sh_inv[N];
  __shared__ __align__(16) float sh_rr[N];
  __shared__ __align__(16) float sh_pA[N];
  __shared__ __align__(16) float sh_pB[N];
  __shared__ float sh_red[8];

  const int b = blockIdx.x;
  const int u = b >> 1;
  const int which = b & 1;
  const int t = threadIdx.x;

  const float* score = (which ? sdiv : sndcg) + (size_t)u * N;
  sh_s[t] = score[t];
  if (!which) sh_aux[t] = rel[(size_t)u * N + t];
  __syncthreads();

  // ---- a_sum + counting ranks (stable-tie-broken, matches jnp.argsort) ----
  const float sj = sh_s[t];
  float asum = 0.f;
  int ltc = 0, gtc = 0, eqb = 0;
  {
    const float4* s4 = (const float4*)sh_s;
#pragma unroll 4
    for (int k4 = 0; k4 < N / 4; k4++) {
      float4 q = s4[k4];
      int k = k4 * 4;
      { float d = q.x - sj; asum += fabsf(d); ltc += (q.x < sj); gtc += (q.x > sj); eqb += ((q.x == sj) && (k + 0 < t)); }
      { float d = q.y - sj; asum += fabsf(d); ltc += (q.y < sj); gtc += (q.y > sj); eqb += ((q.y == sj) && (k + 1 < t)); }
      { float d = q.z - sj; asum += fabsf(d); ltc += (q.z < sj); gtc += (q.z > sj); eqb += ((q.z == sj) && (k + 2 < t)); }
      { float d = q.w - sj; asum += fabsf(d); ltc += (q.w < sj); gtc += (q.w > sj); eqb += ((q.w == sj) && (k + 3 < t)); }
    }
  }
  sh_qs[t] = sj * L2T;
  sh_u[t] = -asum * L2T;  // cL = 0 initially
  __syncthreads();

  // ---- row max + partition function (softmax over j, log2 domain) ----
  {
    const float vi = 511.f - 2.f * t;
    const float4* qs4 = (const float4*)sh_qs;
    const float4* u4 = (const float4*)sh_u;
    float m = -3.4e38f;
#pragma unroll 2
    for (int j4 = 0; j4 < N / 4; j4++) {
      float4 a = qs4[j4], c = u4[j4];
      m = fmaxf(m, fmaf(vi, a.x, c.x));
      m = fmaxf(m, fmaf(vi, a.y, c.y));
      m = fmaxf(m, fmaf(vi, a.z, c.z));
      m = fmaxf(m, fmaf(vi, a.w, c.w));
    }
    float Z = 0.f;
#pragma unroll 2
    for (int j4 = 0; j4 < N / 4; j4++) {
      float4 a = qs4[j4], c = u4[j4];
      Z += EXP2F(fmaf(vi, a.x, c.x) - m);
      Z += EXP2F(fmaf(vi, a.y, c.y) - m);
      Z += EXP2F(fmaf(vi, a.z, c.z) - m);
      Z += EXP2F(fmaf(vi, a.w, c.w) - m);
    }
    sh_rL[t] = -m - LOG2F(Z);
  }
  __syncthreads();

  // ---- 5 Sinkhorn iterations (col normalize, then row normalize) ----
  const float qsj = sh_qs[t];
#pragma unroll 1
  for (int it = 0; it < 5; it++) {
    {  // column sums: thread t owns column j=t, loops over rows i
      float uj = sh_u[t];
      const float4* rl4 = (const float4*)sh_rL;
      float acc = 0.f;
      float v = 511.f;
#pragma unroll 4
      for (int i4 = 0; i4 < N / 4; i4++) {
        float4 r = rl4[i4];
        acc += EXP2F(fmaf(v, qsj, r.x) + uj); v -= 2.f;
        acc += EXP2F(fmaf(v, qsj, r.y) + uj); v -= 2.f;
        acc += EXP2F(fmaf(v, qsj, r.z) + uj); v -= 2.f;
        acc += EXP2F(fmaf(v, qsj, r.w) + uj); v -= 2.f;
      }
      sh_u[t] = uj - LOG2F(fmaxf(acc, 1e-10f));
    }
    __syncthreads();
    {  // row sums: thread t owns row i=t, loops over columns j
      const float vi = 511.f - 2.f * t;
      float rli = sh_rL[t];
      const float4* qs4 = (const float4*)sh_qs;
      const float4* u4 = (const float4*)sh_u;
      float acc = 0.f;
#pragma unroll 2
      for (int j4 = 0; j4 < N / 4; j4++) {
        float4 a = qs4[j4], c = u4[j4];
        acc += EXP2F(fmaf(vi, a.x, c.x) + rli);
        acc += EXP2F(fmaf(vi, a.y, c.y) + rli);
        acc += EXP2F(fmaf(vi, a.z, c.z) + rli);
        acc += EXP2F(fmaf(vi, a.w, c.w) + rli);
      }
      sh_rL[t] = rli - LOG2F(fmaxf(acc, 1e-10f));
    }
    __syncthreads();
  }

  if (which == 0) {
    // ===================== NDCG path =====================
    const float uj = sh_u[t];
    const float relj = sh_aux[t];
    float adcg = 0.f;
#pragma unroll 1
    for (int r = 0; r < TOPK; r++) {
      // approx_rel[r] = sum_j p[r][j]*rel[j]
      float part = EXP2F(fmaf(511.f - 2.f * (float)r, qsj, sh_rL[r]) + uj) * relj;
      float srel = block_reduce_sum(part, sh_red);
      adcg += (EXP2F(srel) - 1.f) / LOG2F((float)(r + 2));
    }
    // dcg at model order: item t sits at descending position gtc+eqb
    int cdesc = gtc + eqb;
    float contrib =
        (cdesc < TOPK) ? (EXP2F(relj) - 1.f) / LOG2F((float)(cdesc + 2)) : 0.f;
    float dcg = block_reduce_sum(contrib, sh_red);
    // best dcg: rank relevance itself
    int bg = 0, be = 0;
    {
      const float4* r4 = (const float4*)sh_aux;
#pragma unroll 4
      for (int k4 = 0; k4 < N / 4; k4++) {
        float4 q = r4[k4];
        int k = k4 * 4;
        bg += (q.x > relj); be += ((q.x == relj) && (k + 0 < t));
        bg += (q.y > relj); be += ((q.y == relj) && (k + 1 < t));
        bg += (q.z > relj); be += ((q.z == relj) && (k + 2 < t));
        bg += (q.w > relj); be += ((q.w == relj) && (k + 3 < t));
      }
    }
    int bidx = bg + be;
    contrib =
        (bidx < TOPK) ? (EXP2F(relj) - 1.f) / LOG2F((float)(bidx + 2)) : 0.f;
    float bdcg = block_reduce_sum(contrib, sh_red);
    if (t == 0) {
      out[u] = adcg / bdcg;
      out[U_CNT + u] = dcg / bdcg;
    }
  } else {
    // ===================== Diversity path =====================
    const float uj = sh_u[t];
    // approx_rank[j] = sum_i w_i * p[i][j], w_i = 512 - i
    float acc = 0.f, v = 511.f, w = 512.f;
    {
      const float4* rl4 = (const float4*)sh_rL;
#pragma unroll 4
      for (int i4 = 0; i4 < N / 4; i4++) {
        float4 r = rl4[i4];
        acc = fmaf(w, EXP2F(fmaf(v, qsj, r.x) + uj), acc); v -= 2.f; w -= 1.f;
        acc = fmaf(w, EXP2F(fmaf(v, qsj, r.y) + uj), acc); v -= 2.f; w -= 1.f;
        acc = fmaf(w, EXP2F(fmaf(v, qsj, r.z) + uj), acc); v -= 2.f; w -= 1.f;
        acc = fmaf(w, EXP2F(fmaf(v, qsj, r.w) + uj), acc); v -= 2.f; w -= 1.f;
      }
    }
    // sigmoid(acc - 502)
    float arj = 1.f / (1.f + EXP2F((502.f - acc) * LOG2E));
    // real rank: ascending 0-based rank >= 502 -> top-10 indicator
    float rrj = ((ltc + eqb) >= 502) ? 1.f : 0.f;
    sh_aux[t] = arj;
    sh_rr[t] = rrj;
    // normalize this item's 64 features
    const float* it = batch + (size_t)(u * N + t) * F_STRIDE;
    float ssq = 0.f;
    {
      const float4* it4 = (const float4*)it;
#pragma unroll
      for (int f4 = 0; f4 < FUF / 4; f4++) {
        float4 p = it4[f4];
        ssq = fmaf(p.x, p.x, ssq); ssq = fmaf(p.y, p.y, ssq);
        ssq = fmaf(p.z, p.z, ssq); ssq = fmaf(p.w, p.w, ssq);
      }
    }
    float inv = 1.f / fmaxf(sqrtf(ssq), 1e-8f);
    sh_inv[t] = inv;
    float om = 1.f - ssq * inv * inv;  // 1 - ||n||^2 (diag correction)
    float S1a = block_reduce_sum(arj, sh_red);
    float S2a = block_reduce_sum(arj * arj, sh_red);
    float DA = block_reduce_sum(arj * arj * om, sh_red);
    float S1r = block_reduce_sum(rrj, sh_red);
    float DR = block_reduce_sum(rrj * om, sh_red);
    // V = sum_j a_j * n_j (64-dim): wave w handles j-chunk w, lane = feature
    int f = t & 63, c = t >> 6;
    const float* bu = batch + (size_t)u * N * F_STRIDE;
    float va = 0.f, vr = 0.f;
#pragma unroll 4
    for (int jj = 0; jj < 64; jj++) {
      int j2 = (c << 6) + jj;
      float x = bu[(size_t)j2 * F_STRIDE + f] * sh_inv[j2];
      va = fmaf(sh_aux[j2], x, va);
      vr = fmaf(sh_rr[j2], x, vr);
    }
    sh_pA[t] = va;
    sh_pB[t] = vr;
    __syncthreads();
    float qa = 0.f, qr = 0.f;
    if (t < 64) {
      float VA = 0.f, VR = 0.f;
#pragma unroll
      for (int c2 = 0; c2 < 8; c2++) {
        VA += sh_pA[c2 * 64 + t];
        VR += sh_pB[c2 * 64 + t];
      }
      qa = VA * VA;
      qr = VR * VR;
    }
    float VA2 = block_reduce_sum(qa, sh_red);
    float VR2 = block_reduce_sum(qr, sh_red);
    if (t == 0) {
      // sum_{i<j} a_i a_j (1 - n_i.n_j) = 0.5*(S1^2 - ||V||^2 - diag)
      float numA = 0.5f * (S1a * S1a - VA2 - DA);
      float denA = 0.5f * (S1a * S1a - S2a);
      out[2 * U_CNT + u] = numA / denA;
      float numR = 0.5f * (S1r * S1r - VR2 - DR);
      float denR = 0.5f * (S1r * S1r - S1r);
      out[3 * U_CNT + u] = numR / denR;
    }
  }
}

extern "C" void kernel_launch(void* const* d_in, const int* in_sizes, int n_in,
                              void* d_out, int out_size, void* d_ws,
                              size_t ws_size, hipStream_t stream) {
  (void)in_sizes; (void)n_in; (void)d_ws; (void)ws_size; (void)out_size;
  const float* batch = (const float*)d_in[0];
  const float* sdiv = (const float*)d_in[1];
  const float* sndcg = (const float*)d_in[2];
  const float* rel = (const float*)d_in[3];
  float* out = (float*)d_out;
  loss_kernel<<<dim3(U_CNT * 2), dim3(N), 0, stream>>>(batch, sdiv, sndcg, rel,
                                                       out);
}

// Round 4
// 143.683 us; speedup vs baseline: 1.1466x; 1.1466x over previous
//
#include <hip/hip_runtime.h>

#define N 512
#define U_CNT 128
#define F_STRIDE 80
#define FUF 64
#define TOPK 10
// log2(e)/tau with tau = 0.1
#define L2T 14.426950408889634f
#define LOG2E 1.4426950408889634f

#if defined(__has_builtin)
#if __has_builtin(__builtin_amdgcn_exp2f)
#define EXP2F(x) __builtin_amdgcn_exp2f(x)
#endif
#if __has_builtin(__builtin_amdgcn_logf)
#define LOG2F(x) __builtin_amdgcn_logf(x)
#endif
#endif
#ifndef EXP2F
#define EXP2F(x) exp2f(x)
#endif
#ifndef LOG2F
#define LOG2F(x) log2f(x)
#endif

// 1024-thread block reduce (16 waves)
__device__ __forceinline__ float block_reduce_sum(float v, float* buf) {
#pragma unroll
  for (int m = 32; m >= 1; m >>= 1) v += __shfl_xor(v, m, 64);
  __syncthreads();
  if ((threadIdx.x & 63) == 0) buf[threadIdx.x >> 6] = v;
  __syncthreads();
  float r = buf[0];
#pragma unroll
  for (int w2 = 1; w2 < 16; w2++) r += buf[w2];
  return r;
}

// One block per (user, which). 1024 threads: thread (idx = t&511, half = t>>9)
// owns row/col idx and covers half of each 512-long reduction range.
// p[i][j] = exp2(v_i*qs_j + rL_i + u_j), never materialized.
__global__ __launch_bounds__(1024) void loss_kernel(
    const float* __restrict__ batch, const float* __restrict__ sdiv,
    const float* __restrict__ sndcg, const float* __restrict__ rel,
    float* __restrict__ out) {
  __shared__ __align__(16) float sh_s[N];
  __shared__ __align__(16) float sh_qs[N];
  __shared__ __align__(16) float sh_u[N];
  __shared__ __align__(16) float sh_rL[N];
  __shared__ __align__(16) float sh_aux[N];   // rel (ndcg) | arj (div)
  __shared__ __align__(16) float sh_inv[N];
  __shared__ __align__(16) float sh_rr[N];
  __shared__ __align__(16) float sh_pA[2 * N];  // partials
  __shared__ __align__(16) float sh_pB[2 * N];
  __shared__ __align__(16) int sh_cnt[2 * N];
  __shared__ float sh_red[16];

  const int b = blockIdx.x;
  const int u = b >> 1;
  const int which = b & 1;
  const int t = threadIdx.x;
  const int idx = t & (N - 1);
  const int half = t >> 9;

  const float* score = (which ? sdiv : sndcg) + (size_t)u * N;
  if (t < N)
    sh_s[t] = score[t];
  else if (!which)
    sh_aux[idx] = rel[(size_t)u * N + idx];
  __syncthreads();

  // ---- a_sum + counting ranks, split over k-half ----
  const float sj = sh_s[idx];
  float asum = 0.f;
  int ltc = 0, gtc = 0, eqb = 0;
  {
    const float4* s4 = (const float4*)sh_s;
    const int k40 = half * (N / 8);
#pragma unroll 4
    for (int k4 = k40; k4 < k40 + N / 8; k4++) {
      float4 q = s4[k4];
      int k = k4 * 4;
      { float d = q.x - sj; asum += fabsf(d); ltc += (q.x < sj); gtc += (q.x > sj); eqb += ((q.x == sj) && (k + 0 < idx)); }
      { float d = q.y - sj; asum += fabsf(d); ltc += (q.y < sj); gtc += (q.y > sj); eqb += ((q.y == sj) && (k + 1 < idx)); }
      { float d = q.z - sj; asum += fabsf(d); ltc += (q.z < sj); gtc += (q.z > sj); eqb += ((q.z == sj) && (k + 2 < idx)); }
      { float d = q.w - sj; asum += fabsf(d); ltc += (q.w < sj); gtc += (q.w > sj); eqb += ((q.w == sj) && (k + 3 < idx)); }
    }
  }
  sh_pA[t] = asum;
  sh_cnt[t] = (ltc << 20) | (gtc << 10) | eqb;
  __syncthreads();
  if (t < N) {
    asum += sh_pA[t + N];
    int c2 = sh_cnt[t] + sh_cnt[t + N];
    ltc = c2 >> 20;
    gtc = (c2 >> 10) & 1023;
    eqb = c2 & 1023;
    sh_qs[t] = sj * L2T;
    sh_u[t] = -asum * L2T;  // cL = 0 initially
  }
  __syncthreads();
  const float qsj = sh_qs[idx];

  // ---- row softmax (log2 domain), j-range split by half ----
  {
    const float vi = 511.f - 2.f * idx;
    const float4* qs4 = (const float4*)sh_qs;
    const float4* u4 = (const float4*)sh_u;
    const int j40 = half * (N / 8);
    float m = -3.4e38f;
#pragma unroll 4
    for (int j4 = j40; j4 < j40 + N / 8; j4++) {
      float4 a = qs4[j4], c = u4[j4];
      m = fmaxf(m, fmaf(vi, a.x, c.x));
      m = fmaxf(m, fmaf(vi, a.y, c.y));
      m = fmaxf(m, fmaf(vi, a.z, c.z));
      m = fmaxf(m, fmaf(vi, a.w, c.w));
    }
    float Z = 0.f;
#pragma unroll 4
    for (int j4 = j40; j4 < j40 + N / 8; j4++) {
      float4 a = qs4[j4], c = u4[j4];
      Z += EXP2F(fmaf(vi, a.x, c.x) - m);
      Z += EXP2F(fmaf(vi, a.y, c.y) - m);
      Z += EXP2F(fmaf(vi, a.z, c.z) - m);
      Z += EXP2F(fmaf(vi, a.w, c.w) - m);
    }
    sh_pA[t] = m;
    sh_pB[t] = Z;
  }
  __syncthreads();
  if (t < N) {
    float m0 = sh_pA[t], m1 = sh_pA[t + N];
    float Z0 = sh_pB[t], Z1 = sh_pB[t + N];
    float m = fmaxf(m0, m1);
    float Z = Z0 * EXP2F(m0 - m) + Z1 * EXP2F(m1 - m);
    sh_rL[t] = -m - LOG2F(Z);
  }
  __syncthreads();

  // ---- 5 Sinkhorn iterations (col normalize, then row normalize) ----
#pragma unroll 1
  for (int it = 0; it < 5; it++) {
    float uj = sh_u[idx];
    {  // column idx: partial sum over rows i in half-range
      const float4* rl4 = (const float4*)sh_rL;
      const int i40 = half * (N / 8);
      float acc = 0.f;
      float v = 511.f - 512.f * half;
#pragma unroll 4
      for (int i4 = i40; i4 < i40 + N / 8; i4++) {
        float4 r = rl4[i4];
        acc += EXP2F(fmaf(v, qsj, r.x) + uj); v -= 2.f;
        acc += EXP2F(fmaf(v, qsj, r.y) + uj); v -= 2.f;
        acc += EXP2F(fmaf(v, qsj, r.z) + uj); v -= 2.f;
        acc += EXP2F(fmaf(v, qsj, r.w) + uj); v -= 2.f;
      }
      sh_pA[t] = acc;
    }
    __syncthreads();
    if (t < N)
      sh_u[t] = uj - LOG2F(fmaxf(sh_pA[t] + sh_pA[t + N], 1e-10f));
    __syncthreads();
    float rli = sh_rL[idx];
    {  // row idx: partial sum over cols j in half-range
      const float vi = 511.f - 2.f * idx;
      const float4* qs4 = (const float4*)sh_qs;
      const float4* u4 = (const float4*)sh_u;
      const int j40 = half * (N / 8);
      float acc = 0.f;
#pragma unroll 4
      for (int j4 = j40; j4 < j40 + N / 8; j4++) {
        float4 a = qs4[j4], c = u4[j4];
        acc += EXP2F(fmaf(vi, a.x, c.x) + rli);
        acc += EXP2F(fmaf(vi, a.y, c.y) + rli);
        acc += EXP2F(fmaf(vi, a.z, c.z) + rli);
        acc += EXP2F(fmaf(vi, a.w, c.w) + rli);
      }
      sh_pA[t] = acc;
    }
    __syncthreads();
    if (t < N)
      sh_rL[t] = rli - LOG2F(fmaxf(sh_pA[t] + sh_pA[t + N], 1e-10f));
    __syncthreads();
  }

  if (which == 0) {
    // ===================== NDCG path =====================
    const float uj = sh_u[idx];
    const float relv = sh_aux[idx];
    float adcg = 0.f;
#pragma unroll 1
    for (int r = 0; r < TOPK; r++) {
      float part = (t < N)
          ? EXP2F(fmaf(511.f - 2.f * (float)r, qsj, sh_rL[r]) + uj) * relv
          : 0.f;
      float srel = block_reduce_sum(part, sh_red);
      adcg += (EXP2F(srel) - 1.f) / LOG2F((float)(r + 2));
    }
    // dcg at model order: item idx sits at descending position gtc+eqb
    int cdesc = gtc + eqb;  // valid on t<N only
    float contrib = (t < N && cdesc < TOPK)
                        ? (EXP2F(relv) - 1.f) / LOG2F((float)(cdesc + 2))
                        : 0.f;
    float dcg = block_reduce_sum(contrib, sh_red);
    // best dcg: rank relevance itself (split over k-half)
    int bg = 0, be = 0;
    {
      const float4* r4 = (const float4*)sh_aux;
      const int k40 = half * (N / 8);
#pragma unroll 4
      for (int k4 = k40; k4 < k40 + N / 8; k4++) {
        float4 q = r4[k4];
        int k = k4 * 4;
        bg += (q.x > relv); be += ((q.x == relv) && (k + 0 < idx));
        bg += (q.y > relv); be += ((q.y == relv) && (k + 1 < idx));
        bg += (q.z > relv); be += ((q.z == relv) && (k + 2 < idx));
        bg += (q.w > relv); be += ((q.w == relv) && (k + 3 < idx));
      }
    }
    sh_cnt[t] = (bg << 10) | be;
    __syncthreads();
    int bidx = 0;
    if (t < N) {
      int c2 = sh_cnt[t] + sh_cnt[t + N];
      bidx = (c2 >> 10) + (c2 & 1023);
    }
    contrib = (t < N && bidx < TOPK)
                  ? (EXP2F(relv) - 1.f) / LOG2F((float)(bidx + 2))
                  : 0.f;
    float bdcg = block_reduce_sum(contrib, sh_red);
    if (t == 0) {
      out[u] = adcg / bdcg;
      out[U_CNT + u] = dcg / bdcg;
    }
  } else {
    // ===================== Diversity path =====================
    const float uj = sh_u[idx];
    {  // approx_rank col idx: partial over i-half, weight w_i = 512 - i
      const float4* rl4 = (const float4*)sh_rL;
      const int i40 = half * (N / 8);
      float acc = 0.f;
      float v = 511.f - 512.f * half;
      float w = 512.f - 256.f * half;
#pragma unroll 4
      for (int i4 = i40; i4 < i40 + N / 8; i4++) {
        float4 r = rl4[i4];
        acc = fmaf(w, EXP2F(fmaf(v, qsj, r.x) + uj), acc); v -= 2.f; w -= 1.f;
        acc = fmaf(w, EXP2F(fmaf(v, qsj, r.y) + uj), acc); v -= 2.f; w -= 1.f;
        acc = fmaf(w, EXP2F(fmaf(v, qsj, r.z) + uj), acc); v -= 2.f; w -= 1.f;
        acc = fmaf(w, EXP2F(fmaf(v, qsj, r.w) + uj), acc); v -= 2.f; w -= 1.f;
      }
      sh_pA[t] = acc;
    }
    // item norm: (idx, half) handles 32 of the 64 user features
    float ssq = 0.f;
    {
      const float4* it4 =
          (const float4*)(batch + (size_t)(u * N + idx) * F_STRIDE + half * 32);
#pragma unroll
      for (int f4 = 0; f4 < 8; f4++) {
        float4 p = it4[f4];
        ssq = fmaf(p.x, p.x, ssq); ssq = fmaf(p.y, p.y, ssq);
        ssq = fmaf(p.z, p.z, ssq); ssq = fmaf(p.w, p.w, ssq);
      }
    }
    sh_pB[t] = ssq;
    __syncthreads();
    float arj = 0.f, rrj = 0.f, om = 0.f;
    if (t < N) {
      float ar = sh_pA[t] + sh_pA[t + N];
      arj = 1.f / (1.f + EXP2F((502.f - ar) * LOG2E));  // sigmoid(ar-502)
      rrj = ((ltc + eqb) >= 502) ? 1.f : 0.f;           // top-10 indicator
      sh_aux[t] = arj;
      sh_rr[t] = rrj;
      float ss = sh_pB[t] + sh_pB[t + N];
      float inv = 1.f / fmaxf(sqrtf(ss), 1e-8f);
      sh_inv[t] = inv;
      om = 1.f - ss * inv * inv;  // 1 - ||n||^2 (diag correction)
    }
    float S1a = block_reduce_sum(arj, sh_red);
    float S2a = block_reduce_sum(arj * arj, sh_red);
    float DA = block_reduce_sum(arj * arj * om, sh_red);
    float S1r = block_reduce_sum(rrj, sh_red);
    float DR = block_reduce_sum(rrj * om, sh_red);
    // V = sum_j a_j * n_j (64-dim): chunk c = t>>6 handles 32 j's, lane = feat
    int f = t & 63, c = t >> 6;
    const float* bu = batch + (size_t)u * N * F_STRIDE;
    float va = 0.f, vr = 0.f;
#pragma unroll 4
    for (int jj = 0; jj < 32; jj++) {
      int j2 = (c << 5) + jj;
      float x = bu[(size_t)j2 * F_STRIDE + f] * sh_inv[j2];
      va = fmaf(sh_aux[j2], x, va);
      vr = fmaf(sh_rr[j2], x, vr);
    }
    sh_pA[t] = va;
    sh_pB[t] = vr;
    __syncthreads();
    float qa = 0.f, qr = 0.f;
    if (t < 64) {
      float VA = 0.f, VR = 0.f;
#pragma unroll
      for (int c2 = 0; c2 < 16; c2++) {
        VA += sh_pA[c2 * 64 + t];
        VR += sh_pB[c2 * 64 + t];
      }
      qa = VA * VA;
      qr = VR * VR;
    }
    float VA2 = block_reduce_sum(qa, sh_red);
    float VR2 = block_reduce_sum(qr, sh_red);
    if (t == 0) {
      // sum_{i<j} a_i a_j (1 - n_i.n_j) = 0.5*(S1^2 - ||V||^2 - diag)
      float numA = 0.5f * (S1a * S1a - VA2 - DA);
      float denA = 0.5f * (S1a * S1a - S2a);
      out[2 * U_CNT + u] = numA / denA;
      float numR = 0.5f * (S1r * S1r - VR2 - DR);
      float denR = 0.5f * (S1r * S1r - S1r);
      out[3 * U_CNT + u] = numR / denR;
    }
  }
}

extern "C" void kernel_launch(void* const* d_in, const int* in_sizes, int n_in,
                              void* d_out, int out_size, void* d_ws,
                              size_t ws_size, hipStream_t stream) {
  (void)in_sizes; (void)n_in; (void)d_ws; (void)ws_size; (void)out_size;
  const float* batch = (const float*)d_in[0];
  const float* sdiv = (const float*)d_in[1];
  const float* sndcg = (const float*)d_in[2];
  const float* rel = (const float*)d_in[3];
  float* out = (float*)d_out;
  loss_kernel<<<dim3(U_CNT * 2), dim3(2 * N), 0, stream>>>(batch, sdiv, sndcg,
                                                           rel, out);
}

// Round 5
// 73.570 us; speedup vs baseline: 2.2392x; 1.9530x over previous
//
#include <hip/hip_runtime.h>

#define N 512
#define U_CNT 128
#define F_STRIDE 80
#define TOPK 10
#define W 80                  // half band width (sorted space)
#define PAD 96
#define BSZ (PAD + N + PAD)   // 704
// log2(e)/tau with tau = 0.1
#define L2T 14.426950408889634f
#define LOG2E 1.4426950408889634f
#define NEGBIG -1.0e30f

#if defined(__has_builtin)
#if __has_builtin(__builtin_amdgcn_exp2f)
#define EXP2F(x) __builtin_amdgcn_exp2f(x)
#endif
#if __has_builtin(__builtin_amdgcn_logf)
#define LOG2F(x) __builtin_amdgcn_logf(x)
#endif
#endif
#ifndef EXP2F
#define EXP2F(x) exp2f(x)
#endif
#ifndef LOG2F
#define LOG2F(x) log2f(x)
#endif

__device__ __forceinline__ float block_reduce_sum(float v, float* buf) {
#pragma unroll
  for (int m = 32; m >= 1; m >>= 1) v += __shfl_xor(v, m, 64);
  __syncthreads();
  if ((threadIdx.x & 63) == 0) buf[threadIdx.x >> 6] = v;
  __syncthreads();
  float r = buf[0];
#pragma unroll
  for (int w2 = 1; w2 < 16; w2++) r += buf[w2];
  return r;
}

// One block per (user, which). 1024 threads: idx = t&511 owns sorted row/col
// idx, half = t>>9 covers half of the +-W band. All Sinkhorn state lives in
// rank-sorted column space: Qs[r], Uu[r] (cols), Rl[i] (rows), padded with
// exponent -1e30 so out-of-range band elements contribute exp2() = 0.
__global__ __launch_bounds__(1024) void loss_kernel(
    const float* __restrict__ batch, const float* __restrict__ sdiv,
    const float* __restrict__ sndcg, const float* __restrict__ rel,
    float* __restrict__ out) {
  __shared__ __align__(16) float sh_s[N];
  __shared__ __align__(16) int sh_pos[N];        // rank -> orig index
  __shared__ __align__(16) float sh_Qs[BSZ];     // sorted qs (pad 0)
  __shared__ __align__(16) float sh_Uu[BSZ];     // col log-factor (pad -1e30)
  __shared__ __align__(16) float sh_Rl[BSZ];     // row log-factor (pad -1e30)
  __shared__ __align__(16) float sh_lw[BSZ];     // Rl + log2(w) (pad -1e30)
  __shared__ __align__(16) float sh_relS[N];     // rel sorted by score rank
  __shared__ __align__(16) float sh_aux[N];      // rel orig (ndcg) | arj orig (div)
  __shared__ __align__(16) float sh_inv[N];
  __shared__ __align__(16) float sh_rr[N];
  __shared__ __align__(16) float sh_pA[2 * N];
  __shared__ __align__(16) float sh_pB[2 * N];
  __shared__ __align__(16) int sh_cnt[2 * N];
  __shared__ float sh_red[16];

  const int b = blockIdx.x;
  const int u = b >> 1;
  const int which = b & 1;
  const int t = threadIdx.x;
  const int idx = t & (N - 1);
  const int half = t >> 9;

  // pad init (exponent sentinels)
  if (t < PAD) {
    sh_Qs[t] = 0.f; sh_Uu[t] = NEGBIG; sh_Rl[t] = NEGBIG; sh_lw[t] = NEGBIG;
  } else if (t < 2 * PAD) {
    int p = PAD + N + (t - PAD);
    sh_Qs[p] = 0.f; sh_Uu[p] = NEGBIG; sh_Rl[p] = NEGBIG; sh_lw[p] = NEGBIG;
  }

  const float* score = (which ? sdiv : sndcg) + (size_t)u * N;
  if (t < N)
    sh_s[t] = score[t];
  else if (!which)
    sh_aux[idx] = rel[(size_t)u * N + idx];
  __syncthreads();

  // ---- count pass: a_sum + stable descending rank, split over half ----
  const float sj = sh_s[idx];
  float asum = 0.f;
  int gtc = 0, eqb = 0;
  {
    const float4* s4 = (const float4*)sh_s;
    const int k40 = half * (N / 8);
#pragma unroll 8
    for (int k4 = k40; k4 < k40 + N / 8; k4++) {
      float4 q = s4[k4];
      int k = k4 * 4;
      { float d=q.x-sj; asum+=fabsf(d); gtc+=(q.x>sj); eqb+=((q.x==sj)&&(k+0<idx)); }
      { float d=q.y-sj; asum+=fabsf(d); gtc+=(q.y>sj); eqb+=((q.y==sj)&&(k+1<idx)); }
      { float d=q.z-sj; asum+=fabsf(d); gtc+=(q.z>sj); eqb+=((q.z==sj)&&(k+2<idx)); }
      { float d=q.w-sj; asum+=fabsf(d); gtc+=(q.w>sj); eqb+=((q.w==sj)&&(k+3<idx)); }
    }
  }
  sh_pA[t] = asum;
  sh_cnt[t] = (gtc << 10) | eqb;
  __syncthreads();
  if (t < N) {
    asum += sh_pA[t + N];
    int c2 = sh_cnt[t] + sh_cnt[t + N];
    int rank = (c2 >> 10) + (c2 & 1023);  // stable descending rank
    sh_Qs[PAD + rank] = sj * L2T;
    sh_Uu[PAD + rank] = -asum * L2T;
    sh_pos[rank] = t;
  }
  __syncthreads();

  // band geometry (float4-aligned, covers [idx-W, idx+W])
  const int base = (idx & ~3) - W;  // in [-80, 428]; PAD+base >= 16, mult of 4
  const int clo = half * 21;
  const int chi = half ? 41 : 21;   // 41 chunks = 164 elements total
  const float vi = 511.f - 2.f * (float)idx;

  // ---- initial row softmax: exact peak at r=idx (unimodal), banded Z ----
  if (t < N && !which) sh_relS[t] = sh_aux[sh_pos[t]];
  float m;
  {
    float e0 = fmaf(vi, sh_Qs[PAD + idx - 1], sh_Uu[PAD + idx - 1]);
    float e1 = fmaf(vi, sh_Qs[PAD + idx], sh_Uu[PAD + idx]);
    float e2 = fmaf(vi, sh_Qs[PAD + idx + 1], sh_Uu[PAD + idx + 1]);
    m = fmaxf(e1, fmaxf(e0, e2));
  }
  {
    const float4* q4 = (const float4*)(sh_Qs + PAD + base);
    const float4* u4 = (const float4*)(sh_Uu + PAD + base);
    float Z = 0.f;
#pragma unroll 4
    for (int c = clo; c < chi; c++) {
      float4 a = q4[c], cc = u4[c];
      Z += EXP2F(fmaf(vi, a.x, cc.x) - m);
      Z += EXP2F(fmaf(vi, a.y, cc.y) - m);
      Z += EXP2F(fmaf(vi, a.z, cc.z) - m);
      Z += EXP2F(fmaf(vi, a.w, cc.w) - m);
    }
    sh_pA[t] = Z;
  }
  __syncthreads();
  if (t < N) sh_Rl[PAD + t] = -m - LOG2F(sh_pA[t] + sh_pA[t + N]);
  __syncthreads();

  // ---- 5 Sinkhorn iterations, banded (col normalize, then row) ----
#pragma unroll 1
  for (int it = 0; it < 5; it++) {
    {  // col pass: column idx, rows i in band; u folded in -> acc = true sum
      const float qsr = sh_Qs[PAD + idx];
      const float c0 = sh_Uu[PAD + idx];
      const float4* r4 = (const float4*)(sh_Rl + PAD + base);
      float acc0 = 0.f, acc1 = 0.f;
      float v = 511.f - 2.f * (float)(base + 4 * clo);
#pragma unroll 4
      for (int c = clo; c < chi; c++) {
        float4 r = r4[c];
        acc0 += EXP2F(fmaf(v, qsr, c0) + r.x); v -= 2.f;
        acc1 += EXP2F(fmaf(v, qsr, c0) + r.y); v -= 2.f;
        acc0 += EXP2F(fmaf(v, qsr, c0) + r.z); v -= 2.f;
        acc1 += EXP2F(fmaf(v, qsr, c0) + r.w); v -= 2.f;
      }
      sh_pA[t] = acc0 + acc1;
    }
    __syncthreads();
    if (t < N)
      sh_Uu[PAD + t] -= LOG2F(fmaxf(sh_pA[t] + sh_pA[t + N], 1e-10f));
    __syncthreads();
    {  // row pass: row idx, cols r in band
      const float rli = sh_Rl[PAD + idx];
      const float4* q4 = (const float4*)(sh_Qs + PAD + base);
      const float4* u4 = (const float4*)(sh_Uu + PAD + base);
      float acc = 0.f;
#pragma unroll 4
      for (int c = clo; c < chi; c++) {
        float4 a = q4[c], cc = u4[c];
        acc += EXP2F(fmaf(vi, a.x, cc.x) + rli);
        acc += EXP2F(fmaf(vi, a.y, cc.y) + rli);
        acc += EXP2F(fmaf(vi, a.z, cc.z) + rli);
        acc += EXP2F(fmaf(vi, a.w, cc.w) + rli);
      }
      sh_pA[t] = acc;
    }
    __syncthreads();
    if (t < N)
      sh_Rl[PAD + t] -= LOG2F(fmaxf(sh_pA[t] + sh_pA[t + N], 1e-10f));
    __syncthreads();
  }

  if (which == 0) {
    // ===================== NDCG path =====================
    const float qsi = sh_Qs[PAD + idx];
    const float uui = sh_Uu[PAD + idx];
    const float relv = (t < N) ? sh_relS[t] : 0.f;
    float adcg = 0.f;
#pragma unroll 1
    for (int r = 0; r < TOPK; r++) {
      float part = 0.f;
      if (t < N && idx <= r + W)  // band of row r
        part = EXP2F(fmaf((float)(511 - 2 * r), qsi, uui) + sh_Rl[PAD + r]) * relv;
      float srel = block_reduce_sum(part, sh_red);
      adcg += (EXP2F(srel) - 1.f) / LOG2F((float)(r + 2));
    }
    // dcg at model order: sorted position t holds the item at desc rank t
    float contrib = (t < TOPK)
        ? (EXP2F(sh_relS[t]) - 1.f) / LOG2F((float)(t + 2)) : 0.f;
    float dcg = block_reduce_sum(contrib, sh_red);
    // best dcg: rank relevance itself (orig space, full range, halves)
    const float rv = sh_aux[idx];
    int bg = 0, be = 0;
    {
      const float4* r4 = (const float4*)sh_aux;
      const int k40 = half * (N / 8);
#pragma unroll 8
      for (int k4 = k40; k4 < k40 + N / 8; k4++) {
        float4 q = r4[k4];
        int k = k4 * 4;
        bg += (q.x > rv); be += ((q.x == rv) && (k + 0 < idx));
        bg += (q.y > rv); be += ((q.y == rv) && (k + 1 < idx));
        bg += (q.z > rv); be += ((q.z == rv) && (k + 2 < idx));
        bg += (q.w > rv); be += ((q.w == rv) && (k + 3 < idx));
      }
    }
    sh_cnt[t] = (bg << 10) | be;
    __syncthreads();
    int bidx = 0;
    if (t < N) {
      int c2 = sh_cnt[t] + sh_cnt[t + N];
      bidx = (c2 >> 10) + (c2 & 1023);
    }
    contrib = (t < N && bidx < TOPK)
        ? (EXP2F(rv) - 1.f) / LOG2F((float)(bidx + 2)) : 0.f;
    float bdcg = block_reduce_sum(contrib, sh_red);
    if (t == 0) {
      out[u] = adcg / bdcg;
      out[U_CNT + u] = dcg / bdcg;
    }
  } else {
    // ===================== Diversity path =====================
    if (t < N) sh_lw[PAD + t] = sh_Rl[PAD + t] + LOG2F((float)(N - t));
    __syncthreads();
    {  // approx_rank col pass, banded, weights folded into exponent
      const float qsr = sh_Qs[PAD + idx];
      const float c0 = sh_Uu[PAD + idx];
      const float4* l4 = (const float4*)(sh_lw + PAD + base);
      float acc0 = 0.f, acc1 = 0.f;
      float v = 511.f - 2.f * (float)(base + 4 * clo);
#pragma unroll 4
      for (int c = clo; c < chi; c++) {
        float4 r = l4[c];
        acc0 += EXP2F(fmaf(v, qsr, c0) + r.x); v -= 2.f;
        acc1 += EXP2F(fmaf(v, qsr, c0) + r.y); v -= 2.f;
        acc0 += EXP2F(fmaf(v, qsr, c0) + r.z); v -= 2.f;
        acc1 += EXP2F(fmaf(v, qsr, c0) + r.w); v -= 2.f;
      }
      sh_pA[t] = acc0 + acc1;
    }
    // item norm partials: (idx, half) handles 32 of the 64 user features
    float ssq = 0.f;
    {
      const float4* it4 =
          (const float4*)(batch + (size_t)(u * N + idx) * F_STRIDE + half * 32);
#pragma unroll
      for (int f4 = 0; f4 < 8; f4++) {
        float4 p = it4[f4];
        ssq = fmaf(p.x, p.x, ssq); ssq = fmaf(p.y, p.y, ssq);
        ssq = fmaf(p.z, p.z, ssq); ssq = fmaf(p.w, p.w, ssq);
      }
    }
    sh_pB[t] = ssq;
    __syncthreads();
    if (t < N) {
      float ar = sh_pA[t] + sh_pA[t + N];
      float arj_s = 1.f / (1.f + EXP2F((502.f - ar) * LOG2E));
      int o = sh_pos[t];
      sh_aux[o] = arj_s;                    // scatter to orig item index
      sh_rr[o] = (t < TOPK) ? 1.f : 0.f;    // desc rank <= 9 -> top-10
      float ss = sh_pB[t] + sh_pB[t + N];
      sh_inv[t] = 1.f / fmaxf(sqrtf(ss), 1e-8f);
      sh_pB[t] = ss;                        // keep combined ssq for om
    }
    __syncthreads();
    float arj = 0.f, rrj = 0.f, om = 0.f;
    if (t < N) {
      arj = sh_aux[t];
      rrj = sh_rr[t];
      float ss = sh_pB[t];
      float inv = sh_inv[t];
      om = 1.f - ss * inv * inv;  // 1 - ||n||^2 diag correction
    }
    float S1a = block_reduce_sum(arj, sh_red);
    float S2a = block_reduce_sum(arj * arj, sh_red);
    float DA = block_reduce_sum(arj * arj * om, sh_red);
    float S1r = block_reduce_sum(rrj, sh_red);
    float DR = block_reduce_sum(rrj * om, sh_red);
    // V = sum_j a_j * n_j (64-dim): chunk c = t>>6 handles 32 j's, lane = feat
    int f = t & 63, c = t >> 6;
    const float* bu = batch + (size_t)u * N * F_STRIDE;
    float va = 0.f, vr = 0.f;
#pragma unroll 4
    for (int jj = 0; jj < 32; jj++) {
      int j2 = (c << 5) + jj;
      float x = bu[(size_t)j2 * F_STRIDE + f] * sh_inv[j2];
      va = fmaf(sh_aux[j2], x, va);
      vr = fmaf(sh_rr[j2], x, vr);
    }
    sh_pA[t] = va;
    sh_pB[t] = vr;
    __syncthreads();
    float qa = 0.f, qr = 0.f;
    if (t < 64) {
      float VA = 0.f, VR = 0.f;
#pragma unroll
      for (int c2 = 0; c2 < 16; c2++) {
        VA += sh_pA[c2 * 64 + t];
        VR += sh_pB[c2 * 64 + t];
      }
      qa = VA * VA;
      qr = VR * VR;
    }
    float VA2 = block_reduce_sum(qa, sh_red);
    float VR2 = block_reduce_sum(qr, sh_red);
    if (t == 0) {
      float numA = 0.5f * (S1a * S1a - VA2 - DA);
      float denA = 0.5f * (S1a * S1a - S2a);
      out[2 * U_CNT + u] = numA / denA;
      float numR = 0.5f * (S1r * S1r - VR2 - DR);
      float denR = 0.5f * (S1r * S1r - S1r);
      out[3 * U_CNT + u] = numR / denR;
    }
  }
}

extern "C" void kernel_launch(void* const* d_in, const int* in_sizes, int n_in,
                              void* d_out, int out_size, void* d_ws,
                              size_t ws_size, hipStream_t stream) {
  (void)in_sizes; (void)n_in; (void)d_ws; (void)ws_size; (void)out_size;
  const float* batch = (const float*)d_in[0];
  const float* sdiv = (const float*)d_in[1];
  const float* sndcg = (const float*)d_in[2];
  const float* rel = (const float*)d_in[3];
  float* out = (float*)d_out;
  loss_kernel<<<dim3(U_CNT * 2), dim3(2 * N), 0, stream>>>(batch, sdiv, sndcg,
                                                           rel, out);
}

// Round 6
// 61.754 us; speedup vs baseline: 2.6677x; 1.1913x over previous
//
#include <hip/hip_runtime.h>

#define N 512
#define U_CNT 128
#define F_STRIDE 80
#define TOPK 10
#define W 64                  // half band width (sorted space)
#define PAD 96
#define BSZ (PAD + N + PAD)   // 704
#define NCH ((2 * W + 4) / 4) // 33 band float4 chunks
// log2(e)/tau with tau = 0.1
#define L2T 14.426950408889634f
#define LOG2E 1.4426950408889634f
#define NEGBIG -1.0e30f

#if defined(__has_builtin)
#if __has_builtin(__builtin_amdgcn_exp2f)
#define EXP2F(x) __builtin_amdgcn_exp2f(x)
#endif
#if __has_builtin(__builtin_amdgcn_logf)
#define LOG2F(x) __builtin_amdgcn_logf(x)
#endif
#endif
#ifndef EXP2F
#define EXP2F(x) exp2f(x)
#endif
#ifndef LOG2F
#define LOG2F(x) log2f(x)
#endif

__device__ __forceinline__ float wave_reduce(float v) {
#pragma unroll
  for (int m = 32; m >= 1; m >>= 1) v += __shfl_xor(v, m, 64);
  return v;
}

// One block per (user, which). 1024 threads: idx = t&511 owns sorted row/col
// idx, half = t>>9 covers half of the +-W band. Sinkhorn state in rank-sorted
// space: Qs, Uu (cols), Rl (rows), padded with -1e30 so out-of-range band
// elements give exp2() = 0. Band truncation beyond W is exact (f32 underflow).
__global__ __launch_bounds__(1024) void loss_kernel(
    const float* __restrict__ batch, const float* __restrict__ sdiv,
    const float* __restrict__ sndcg, const float* __restrict__ rel,
    float* __restrict__ out) {
  __shared__ __align__(16) float sh_s[N];
  __shared__ __align__(16) int sh_pos[N];     // rank -> orig index
  __shared__ __align__(16) float sh_Qs[BSZ];  // sorted qs (pad 0)
  __shared__ __align__(16) float sh_Uu[BSZ];  // col log-factor (pad -1e30)
  __shared__ __align__(16) float sh_Rl[BSZ];  // row log-factor (pad -1e30)
  __shared__ __align__(16) float sh_lw[BSZ];  // Rl + log2(w) (pad -1e30)
  __shared__ __align__(16) float sh_relS[N];  // rel sorted by score rank
  __shared__ __align__(16) float sh_aux[N];   // rel orig (ndcg) | arj orig (div)
  __shared__ __align__(16) float sh_inv[N];
  __shared__ __align__(16) float sh_rr[N];
  __shared__ __align__(16) float sh_pA[2 * N];
  __shared__ __align__(16) float sh_pB[2 * N];
  __shared__ __align__(16) int sh_cnt[2 * N];
  __shared__ float sh_row[TOPK];
  __shared__ float sh_w1[16], sh_w2[16], sh_w3[16], sh_w4[16], sh_w5[16];

  const int b = blockIdx.x;
  const int u = b >> 1;
  const int which = b & 1;
  const int t = threadIdx.x;
  const int idx = t & (N - 1);
  const int half = t >> 9;
  const int wv = t >> 6;
  const int ln = t & 63;

  // pad init (exponent sentinels)
  if (t < PAD) {
    sh_Qs[t] = 0.f; sh_Uu[t] = NEGBIG; sh_Rl[t] = NEGBIG; sh_lw[t] = NEGBIG;
  } else if (t < 2 * PAD) {
    int p = PAD + N + (t - PAD);
    sh_Qs[p] = 0.f; sh_Uu[p] = NEGBIG; sh_Rl[p] = NEGBIG; sh_lw[p] = NEGBIG;
  }

  const float* score = (which ? sdiv : sndcg) + (size_t)u * N;
  if (t < N)
    sh_s[t] = score[t];
  else if (!which)
    sh_aux[idx] = rel[(size_t)u * N + idx];
  if (which) {
    // early item-norm partials: (idx, half) covers 32 of 64 user features;
    // issues global loads now so latency hides under the count pass.
    const float4* it4 =
        (const float4*)(batch + (size_t)(u * N + idx) * F_STRIDE + half * 32);
    float ssq = 0.f;
#pragma unroll
    for (int f4 = 0; f4 < 8; f4++) {
      float4 p = it4[f4];
      ssq = fmaf(p.x, p.x, ssq); ssq = fmaf(p.y, p.y, ssq);
      ssq = fmaf(p.z, p.z, ssq); ssq = fmaf(p.w, p.w, ssq);
    }
    sh_pB[t] = ssq;  // pB untouched until div tail
  }
  __syncthreads();

  // ---- count pass: a_sum + stable descending rank, split over half ----
  const float sj = sh_s[idx];
  float asum = 0.f;
  int gtc = 0, eqb = 0;
  {
    const float4* s4 = (const float4*)sh_s;
    const int k40 = half * (N / 8);
#pragma unroll 8
    for (int k4 = k40; k4 < k40 + N / 8; k4++) {
      float4 q = s4[k4];
      int k = k4 * 4;
      { float d=q.x-sj; asum+=fabsf(d); gtc+=(q.x>sj); eqb+=((q.x==sj)&&(k+0<idx)); }
      { float d=q.y-sj; asum+=fabsf(d); gtc+=(q.y>sj); eqb+=((q.y==sj)&&(k+1<idx)); }
      { float d=q.z-sj; asum+=fabsf(d); gtc+=(q.z>sj); eqb+=((q.z==sj)&&(k+2<idx)); }
      { float d=q.w-sj; asum+=fabsf(d); gtc+=(q.w>sj); eqb+=((q.w==sj)&&(k+3<idx)); }
    }
  }
  sh_pA[t] = asum;
  sh_cnt[t] = (gtc << 10) | eqb;
  __syncthreads();
  if (t < N) {
    asum += sh_pA[t + N];
    int c2 = sh_cnt[t] + sh_cnt[t + N];
    int rank = (c2 >> 10) + (c2 & 1023);  // stable descending rank
    sh_Qs[PAD + rank] = sj * L2T;
    sh_Uu[PAD + rank] = -asum * L2T;
    sh_pos[rank] = t;
  }
  __syncthreads();

  // band geometry (float4-aligned, covers [idx-W, idx+W])
  const int base = (idx & ~3) - W;  // PAD+base >= 32, multiple of 4
  const int clo = half * 17;
  const int chi = half ? NCH : 17;
  const float vi = 511.f - 2.f * (float)idx;

  if (t < N && !which) sh_relS[t] = sh_aux[sh_pos[t]];

  // ---- initial row softmax: exact peak at r=idx (unimodal), banded Z ----
  float m;
  {
    float e0 = fmaf(vi, sh_Qs[PAD + idx - 1], sh_Uu[PAD + idx - 1]);
    float e1 = fmaf(vi, sh_Qs[PAD + idx], sh_Uu[PAD + idx]);
    float e2 = fmaf(vi, sh_Qs[PAD + idx + 1], sh_Uu[PAD + idx + 1]);
    m = fmaxf(e1, fmaxf(e0, e2));
  }
  {
    const float4* q4 = (const float4*)(sh_Qs + PAD + base);
    const float4* u4 = (const float4*)(sh_Uu + PAD + base);
    float Z = 0.f;
#pragma unroll 4
    for (int c = clo; c < chi; c++) {
      float4 a = q4[c], cc = u4[c];
      Z += EXP2F(fmaf(vi, a.x, cc.x) - m);
      Z += EXP2F(fmaf(vi, a.y, cc.y) - m);
      Z += EXP2F(fmaf(vi, a.z, cc.z) - m);
      Z += EXP2F(fmaf(vi, a.w, cc.w) - m);
    }
    sh_pA[t] = Z;
  }
  __syncthreads();
  if (t < N) sh_Rl[PAD + t] = -m - LOG2F(sh_pA[t] + sh_pA[t + N]);
  __syncthreads();

  // ---- 5 Sinkhorn iterations, banded (col normalize, then row) ----
#pragma unroll 1
  for (int it = 0; it < 5; it++) {
    {  // col pass: column idx, rows i in band; u folded -> acc = true col sum
      const float qsr = sh_Qs[PAD + idx];
      const float c0 = sh_Uu[PAD + idx];
      const float4* r4 = (const float4*)(sh_Rl + PAD + base);
      float acc0 = 0.f, acc1 = 0.f;
      float v = 511.f - 2.f * (float)(base + 4 * clo);
#pragma unroll 4
      for (int c = clo; c < chi; c++) {
        float4 r = r4[c];
        acc0 += EXP2F(fmaf(v, qsr, c0) + r.x); v -= 2.f;
        acc1 += EXP2F(fmaf(v, qsr, c0) + r.y); v -= 2.f;
        acc0 += EXP2F(fmaf(v, qsr, c0) + r.z); v -= 2.f;
        acc1 += EXP2F(fmaf(v, qsr, c0) + r.w); v -= 2.f;
      }
      sh_pA[t] = acc0 + acc1;
    }
    __syncthreads();
    if (t < N)
      sh_Uu[PAD + t] -= LOG2F(fmaxf(sh_pA[t] + sh_pA[t + N], 1e-10f));
    __syncthreads();
    {  // row pass: row idx, cols r in band
      const float rli = sh_Rl[PAD + idx];
      const float4* q4 = (const float4*)(sh_Qs + PAD + base);
      const float4* u4 = (const float4*)(sh_Uu + PAD + base);
      float acc = 0.f;
#pragma unroll 4
      for (int c = clo; c < chi; c++) {
        float4 a = q4[c], cc = u4[c];
        acc += EXP2F(fmaf(vi, a.x, cc.x) + rli);
        acc += EXP2F(fmaf(vi, a.y, cc.y) + rli);
        acc += EXP2F(fmaf(vi, a.z, cc.z) + rli);
        acc += EXP2F(fmaf(vi, a.w, cc.w) + rli);
      }
      sh_pA[t] = acc;
    }
    __syncthreads();
    if (t < N) {
      float nr = sh_Rl[PAD + t] - LOG2F(fmaxf(sh_pA[t] + sh_pA[t + N], 1e-10f));
      sh_Rl[PAD + t] = nr;
      if (which && it == 4)  // fold lw for div's approx_rank pass
        sh_lw[PAD + t] = nr + LOG2F((float)(N - t));
    }
    __syncthreads();
  }

  if (which == 0) {
    // ===================== NDCG path =====================
    // wave-per-row approx_rel: wave r (r<10) owns p-row r's band, no barriers
    if (wv < TOPK) {
      const int r = wv;
      const float cv = 511.f - 2.f * (float)r;
      const float rl = sh_Rl[PAD + r];
      const int rbase = (r & ~3) - W;
      float srel = 0.f;
#pragma unroll
      for (int k = 0; k < 3; k++) {
        int e = ln + 64 * k;
        if (e < 2 * W + 4) {
          int j = rbase + e;
          float ex = fmaf(cv, sh_Qs[PAD + j], sh_Uu[PAD + j]) + rl;
          float rv2 = ((unsigned)j < N) ? sh_relS[j] : 0.f;
          srel = fmaf(EXP2F(ex), rv2, srel);
        }
      }
      srel = wave_reduce(srel);
      if (ln == 0) sh_row[r] = srel;
    }
    // dcg contrib: sorted position t holds the item at descending rank t
    float cd = (t < TOPK)
        ? (EXP2F(sh_relS[t]) - 1.f) / LOG2F((float)(t + 2)) : 0.f;
    // bdcg: rank relevance itself (orig space, split halves)
    const float rv = sh_aux[idx];
    int bg = 0, be = 0;
    {
      const float4* r4 = (const float4*)sh_aux;
      const int k40 = half * (N / 8);
#pragma unroll 8
      for (int k4 = k40; k4 < k40 + N / 8; k4++) {
        float4 q = r4[k4];
        int k = k4 * 4;
        bg += (q.x > rv); be += ((q.x == rv) && (k + 0 < idx));
        bg += (q.y > rv); be += ((q.y == rv) && (k + 1 < idx));
        bg += (q.z > rv); be += ((q.z == rv) && (k + 2 < idx));
        bg += (q.w > rv); be += ((q.w == rv) && (k + 3 < idx));
      }
    }
    sh_cnt[t] = (bg << 10) | be;
    __syncthreads();
    float cb = 0.f;
    if (t < N) {
      int c2 = sh_cnt[t] + sh_cnt[t + N];
      int bidx = (c2 >> 10) + (c2 & 1023);
      if (bidx < TOPK) cb = (EXP2F(rv) - 1.f) / LOG2F((float)(bidx + 2));
    }
    // dual interleaved wave reduce (dcg, bdcg)
#pragma unroll
    for (int mm = 32; mm >= 1; mm >>= 1) {
      cd += __shfl_xor(cd, mm, 64);
      cb += __shfl_xor(cb, mm, 64);
    }
    if (ln == 0) { sh_w1[wv] = cd; sh_w2[wv] = cb; }
    __syncthreads();
    if (t == 0) {
      float adcg = 0.f;
#pragma unroll
      for (int r = 0; r < TOPK; r++)
        adcg += (EXP2F(sh_row[r]) - 1.f) / LOG2F((float)(r + 2));
      float dcg = 0.f, bdcg = 0.f;
#pragma unroll
      for (int w2 = 0; w2 < 16; w2++) { dcg += sh_w1[w2]; bdcg += sh_w2[w2]; }
      out[u] = adcg / bdcg;
      out[U_CNT + u] = dcg / bdcg;
    }
  } else {
    // ===================== Diversity path =====================
    {  // approx_rank col pass, banded, weights folded (sh_lw)
      const float qsr = sh_Qs[PAD + idx];
      const float c0 = sh_Uu[PAD + idx];
      const float4* l4 = (const float4*)(sh_lw + PAD + base);
      float acc0 = 0.f, acc1 = 0.f;
      float v = 511.f - 2.f * (float)(base + 4 * clo);
#pragma unroll 4
      for (int c = clo; c < chi; c++) {
        float4 r = l4[c];
        acc0 += EXP2F(fmaf(v, qsr, c0) + r.x); v -= 2.f;
        acc1 += EXP2F(fmaf(v, qsr, c0) + r.y); v -= 2.f;
        acc0 += EXP2F(fmaf(v, qsr, c0) + r.z); v -= 2.f;
        acc1 += EXP2F(fmaf(v, qsr, c0) + r.w); v -= 2.f;
      }
      sh_pA[t] = acc0 + acc1;
    }
    __syncthreads();
    float om = 0.f;
    if (t < N) {
      float ar = sh_pA[t] + sh_pA[t + N];
      float arj_s = 1.f / (1.f + EXP2F((502.f - ar) * LOG2E));  // sigmoid
      int o = sh_pos[t];
      sh_aux[o] = arj_s;                  // scatter to orig item index
      sh_rr[o] = (t < TOPK) ? 1.f : 0.f;  // desc rank < 10 -> top-10
      float ss = sh_pB[t] + sh_pB[t + N];  // orig-index ssq (early partials)
      float inv = 1.f / fmaxf(sqrtf(ss), 1e-8f);
      sh_inv[t] = inv;
      om = 1.f - ss * inv * inv;  // 1 - ||n||^2 for ORIG item t
    }
    __syncthreads();
    float arj = 0.f, rrj = 0.f;
    if (t < N) { arj = sh_aux[t]; rrj = sh_rr[t]; }
    float r1 = arj, r2 = arj * arj, r3 = arj * arj * om, r4v = rrj,
          r5v = rrj * om;
#pragma unroll
    for (int mm = 32; mm >= 1; mm >>= 1) {
      r1 += __shfl_xor(r1, mm, 64);
      r2 += __shfl_xor(r2, mm, 64);
      r3 += __shfl_xor(r3, mm, 64);
      r4v += __shfl_xor(r4v, mm, 64);
      r5v += __shfl_xor(r5v, mm, 64);
    }
    if (ln == 0) {
      sh_w1[wv] = r1; sh_w2[wv] = r2; sh_w3[wv] = r3;
      sh_w4[wv] = r4v; sh_w5[wv] = r5v;
    }
    // V = sum_j a_j * n_j (64-dim): chunk c = t>>6 handles 32 j's, lane = feat
    int f = t & 63, c = t >> 6;
    const float* bu = batch + (size_t)u * N * F_STRIDE;
    float va = 0.f, vr = 0.f;
#pragma unroll 4
    for (int jj = 0; jj < 32; jj++) {
      int j2 = (c << 5) + jj;
      float x = bu[(size_t)j2 * F_STRIDE + f] * sh_inv[j2];
      va = fmaf(sh_aux[j2], x, va);
      vr = fmaf(sh_rr[j2], x, vr);
    }
    sh_pA[t] = va;
    sh_pB[t] = vr;
    __syncthreads();
    float qa = 0.f, qr = 0.f;
    if (t < 64) {
      float VA = 0.f, VR = 0.f;
#pragma unroll
      for (int c2 = 0; c2 < 16; c2++) {
        VA += sh_pA[c2 * 64 + t];
        VR += sh_pB[c2 * 64 + t];
      }
      qa = VA * VA;
      qr = VR * VR;
    }
#pragma unroll
    for (int mm = 32; mm >= 1; mm >>= 1) {
      qa += __shfl_xor(qa, mm, 64);
      qr += __shfl_xor(qr, mm, 64);
    }
    if (t == 0) {  // qa/qr complete in wave 0; sh_w* visible since last bar
      float S1a = 0.f, S2a = 0.f, DA = 0.f, S1r = 0.f, DR = 0.f;
#pragma unroll
      for (int w2 = 0; w2 < 16; w2++) {
        S1a += sh_w1[w2]; S2a += sh_w2[w2]; DA += sh_w3[w2];
        S1r += sh_w4[w2]; DR += sh_w5[w2];
      }
      // sum_{i<j} a_i a_j (1 - n_i.n_j) = 0.5*(S1^2 - ||V||^2 - diag)
      float numA = 0.5f * (S1a * S1a - qa - DA);
      float denA = 0.5f * (S1a * S1a - S2a);
      out[2 * U_CNT + u] = numA / denA;
      float numR = 0.5f * (S1r * S1r - qr - DR);
      float denR = 0.5f * (S1r * S1r - S1r);
      out[3 * U_CNT + u] = numR / denR;
    }
  }
}

extern "C" void kernel_launch(void* const* d_in, const int* in_sizes, int n_in,
                              void* d_out, int out_size, void* d_ws,
                              size_t ws_size, hipStream_t stream) {
  (void)in_sizes; (void)n_in; (void)d_ws; (void)ws_size; (void)out_size;
  const float* batch = (const float*)d_in[0];
  const float* sdiv = (const float*)d_in[1];
  const float* sndcg = (const float*)d_in[2];
  const float* rel = (const float*)d_in[3];
  float* out = (float*)d_out;
  loss_kernel<<<dim3(U_CNT * 2), dim3(2 * N), 0, stream>>>(batch, sdiv, sndcg,
                                                           rel, out);
}

// Round 7
// 57.073 us; speedup vs baseline: 2.8865x; 1.0820x over previous
//
#include <hip/hip_runtime.h>

#define N 512
#define U_CNT 128
#define F_STRIDE 80
#define TOPK 10
#define W 64                  // half band width (sorted space)
#define PAD 96
#define BSZ (PAD + N + PAD)   // 704
#define NCH ((2 * W + 4) / 4) // 33 band float4 chunks
// log2(e)/tau with tau = 0.1
#define L2T 14.426950408889634f
#define LOG2E 1.4426950408889634f
#define NEGBIG -1.0e30f

#if defined(__has_builtin)
#if __has_builtin(__builtin_amdgcn_exp2f)
#define EXP2F(x) __builtin_amdgcn_exp2f(x)
#endif
#if __has_builtin(__builtin_amdgcn_logf)
#define LOG2F(x) __builtin_amdgcn_logf(x)
#endif
#endif
#ifndef EXP2F
#define EXP2F(x) exp2f(x)
#endif
#ifndef LOG2F
#define LOG2F(x) log2f(x)
#endif

// monotone sortable key: ascending key order == descending value order,
// ties broken by smaller idx first (stable, matches jnp.argsort on -score)
__device__ __forceinline__ unsigned long long sortkey(float x, int idx) {
  unsigned int bb = __float_as_uint(x);
  bb ^= (unsigned int)((int)bb >> 31) | 0x80000000u;
  return ((unsigned long long)(~bb) << 10) | (unsigned long long)idx;
}

// One block per (user, which), 512 threads (8 waves). Thread t owns sorted
// row/col t. Sinkhorn state in rank-sorted space: Qs, Uu (cols), Rl (rows),
// padded with -1e30 so out-of-band elements give exp2() = 0 (exact: band
// truncation beyond W=64 underflows to 0.0f in f32).
__global__ __launch_bounds__(512) void loss_kernel(
    const float* __restrict__ batch, const float* __restrict__ sdiv,
    const float* __restrict__ sndcg, const float* __restrict__ rel,
    float* __restrict__ out) {
  __shared__ __align__(16) unsigned long long sh_key[N];
  __shared__ __align__(16) float sh_sv[N];    // sorted raw score
  __shared__ __align__(16) int sh_pos[N];     // rank -> orig index
  __shared__ __align__(16) float sh_Qs[BSZ];  // sorted qs (pad 0)
  __shared__ __align__(16) float sh_Uu[BSZ];  // col log-factor (pad -1e30)
  __shared__ __align__(16) float sh_Rl[BSZ];  // row log-factor (pad -1e30)
  __shared__ __align__(16) float sh_lw[BSZ];  // Rl + log2(w) (pad -1e30)
  __shared__ __align__(16) float sh_relS[N];  // rel sorted by score rank
  __shared__ __align__(16) float sh_aux[N];   // rel orig (ndcg) | arj orig (div)
  __shared__ __align__(16) float sh_inv[N];
  __shared__ __align__(16) float sh_rr[N];
  __shared__ __align__(16) float sh_pA[N];
  __shared__ __align__(16) float sh_pB[N];
  __shared__ float sh_red[8];
  __shared__ float sh_w1[8], sh_w2[8], sh_w3[8], sh_w4[8], sh_w5[8];
  __shared__ float sh_row[TOPK];

  const int b = blockIdx.x;
  const int u = b >> 1;
  const int which = b & 1;
  const int t = threadIdx.x;
  const int wv = t >> 6;
  const int ln = t & 63;

  // pad init (exponent sentinels)
  if (t < PAD) {
    sh_Qs[t] = 0.f; sh_Uu[t] = NEGBIG; sh_Rl[t] = NEGBIG; sh_lw[t] = NEGBIG;
  } else if (t < 2 * PAD) {
    int p = PAD + N + (t - PAD);
    sh_Qs[p] = 0.f; sh_Uu[p] = NEGBIG; sh_Rl[p] = NEGBIG; sh_lw[p] = NEGBIG;
  }

  const float sj = ((which ? sdiv : sndcg) + (size_t)u * N)[t];
  sh_key[t] = sortkey(sj, t);
  if (!which) sh_aux[t] = rel[(size_t)u * N + t];
  float ssq = 0.f;
  if (which) {  // early item-norm: global latency hides under rank pass
    const float4* it4 =
        (const float4*)(batch + (size_t)(u * N + t) * F_STRIDE);
#pragma unroll
    for (int f4 = 0; f4 < 16; f4++) {
      float4 p = it4[f4];
      ssq = fmaf(p.x, p.x, ssq); ssq = fmaf(p.y, p.y, ssq);
      ssq = fmaf(p.z, p.z, ssq); ssq = fmaf(p.w, p.w, ssq);
    }
  }
  __syncthreads();

  // ---- rank pass: stable descending rank via u64 key counting ----
  {
    const unsigned long long myk = sh_key[t];
    const ulonglong2* k2 = (const ulonglong2*)sh_key;
    int rnk = 0;
#pragma unroll 8
    for (int i = 0; i < N / 2; i++) {
      ulonglong2 kk = k2[i];
      rnk += (kk.x < myk);
      rnk += (kk.y < myk);
    }
    sh_sv[rnk] = sj;
    sh_pos[rnk] = t;
  }
  __syncthreads();

  // ---- sorted-space setup: Qs, relS, asum via prefix scan ----
  const float sv = sh_sv[t];
  sh_Qs[PAD + t] = sv * L2T;
  if (!which) sh_relS[t] = sh_aux[sh_pos[t]];
  {
    float ps = sv;  // inclusive wave scan
#pragma unroll
    for (int m = 1; m <= 32; m <<= 1) {
      float o = __shfl_up(ps, m, 64);
      if (ln >= m) ps += o;
    }
    if (ln == 63) sh_red[wv] = ps;
    __syncthreads();
    float off = 0.f, Tt = 0.f;
#pragma unroll
    for (int w2 = 0; w2 < 8; w2++) {
      float rv = sh_red[w2];
      if (w2 < wv) off += rv;
      Tt += rv;
    }
    float S = ps + off;  // inclusive prefix over block (desc sorted)
    float asum = 2.f * S - Tt + (float)(N - 2 - 2 * t) * sv;
    sh_Uu[PAD + t] = -asum * L2T;
  }
  __syncthreads();

  // band geometry (float4-aligned, covers [t-W, t+W])
  const int base = (t & ~3) - W;  // PAD+base >= 32, multiple of 4
  const float vi = 511.f - 2.f * (float)t;

  // ---- initial row softmax: exact peak at col=t (unimodal), banded Z ----
  {
    float e0 = fmaf(vi, sh_Qs[PAD + t - 1], sh_Uu[PAD + t - 1]);
    float e1 = fmaf(vi, sh_Qs[PAD + t], sh_Uu[PAD + t]);
    float e2 = fmaf(vi, sh_Qs[PAD + t + 1], sh_Uu[PAD + t + 1]);
    float m = fmaxf(e1, fmaxf(e0, e2));
    const float4* q4 = (const float4*)(sh_Qs + PAD + base);
    const float4* u4 = (const float4*)(sh_Uu + PAD + base);
    float Z = 0.f;
#pragma unroll 4
    for (int c = 0; c < NCH; c++) {
      float4 a = q4[c], cc = u4[c];
      Z += EXP2F(fmaf(vi, a.x, cc.x) - m);
      Z += EXP2F(fmaf(vi, a.y, cc.y) - m);
      Z += EXP2F(fmaf(vi, a.z, cc.z) - m);
      Z += EXP2F(fmaf(vi, a.w, cc.w) - m);
    }
    sh_Rl[PAD + t] = -m - LOG2F(Z);
  }
  __syncthreads();

  // ---- 5 Sinkhorn iterations, banded (col normalize, then row) ----
#pragma unroll 1
  for (int it = 0; it < 5; it++) {
    {  // col pass: column t, rows i in band; u folded -> acc = true col sum
      const float qsr = sh_Qs[PAD + t];
      const float c0 = sh_Uu[PAD + t];
      const float4* r4 = (const float4*)(sh_Rl + PAD + base);
      float acc0 = 0.f, acc1 = 0.f;
      float v = 511.f - 2.f * (float)base;
#pragma unroll 4
      for (int c = 0; c < NCH; c++) {
        float4 r = r4[c];
        acc0 += EXP2F(fmaf(v, qsr, c0) + r.x); v -= 2.f;
        acc1 += EXP2F(fmaf(v, qsr, c0) + r.y); v -= 2.f;
        acc0 += EXP2F(fmaf(v, qsr, c0) + r.z); v -= 2.f;
        acc1 += EXP2F(fmaf(v, qsr, c0) + r.w); v -= 2.f;
      }
      sh_Uu[PAD + t] = c0 - LOG2F(fmaxf(acc0 + acc1, 1e-10f));
    }
    __syncthreads();
    {  // row pass: row t, cols r in band
      const float rli = sh_Rl[PAD + t];
      const float4* q4 = (const float4*)(sh_Qs + PAD + base);
      const float4* u4 = (const float4*)(sh_Uu + PAD + base);
      float acc = 0.f;
#pragma unroll 4
      for (int c = 0; c < NCH; c++) {
        float4 a = q4[c], cc = u4[c];
        acc += EXP2F(fmaf(vi, a.x, cc.x) + rli);
        acc += EXP2F(fmaf(vi, a.y, cc.y) + rli);
        acc += EXP2F(fmaf(vi, a.z, cc.z) + rli);
        acc += EXP2F(fmaf(vi, a.w, cc.w) + rli);
      }
      float nr = rli - LOG2F(fmaxf(acc, 1e-10f));
      sh_Rl[PAD + t] = nr;
      if (which && it == 4)  // fold lw for div's approx_rank pass
        sh_lw[PAD + t] = nr + LOG2F((float)(N - t));
    }
    __syncthreads();
  }

  if (which == 0) {
    // ===================== NDCG path =====================
    // wave-per-row approx_rel: wave wv owns p-rows wv, wv+8 (bands), no bar
#pragma unroll
    for (int r = wv; r < TOPK; r += 8) {
      const float cv = 511.f - 2.f * (float)r;
      const float rl = sh_Rl[PAD + r];
      const int rbase = (r & ~3) - W;
      float srel = 0.f;
#pragma unroll
      for (int k = 0; k < 3; k++) {
        int e = ln + 64 * k;
        if (e < 2 * W + 4) {
          int j = rbase + e;
          float ex = fmaf(cv, sh_Qs[PAD + j], sh_Uu[PAD + j]) + rl;
          float rv2 = ((unsigned)j < N) ? sh_relS[j] : 0.f;
          srel = fmaf(EXP2F(ex), rv2, srel);
        }
      }
#pragma unroll
      for (int mm = 32; mm >= 1; mm >>= 1) srel += __shfl_xor(srel, mm, 64);
      if (ln == 0) sh_row[r] = srel;
    }
    // dcg contrib: sorted position t holds the item at descending rank t
    float cd = (t < TOPK)
        ? (EXP2F(sh_relS[t]) - 1.f) / LOG2F((float)(t + 2)) : 0.f;
    // bdcg: rel rank via u64 keys (reuse sh_key)
    const float rv = sh_aux[t];
    sh_key[t] = sortkey(rv, t);
    __syncthreads();
    float cb = 0.f;
    {
      const unsigned long long myk = sh_key[t];
      const ulonglong2* k2 = (const ulonglong2*)sh_key;
      int rnk = 0;
#pragma unroll 8
      for (int i = 0; i < N / 2; i++) {
        ulonglong2 kk = k2[i];
        rnk += (kk.x < myk);
        rnk += (kk.y < myk);
      }
      if (rnk < TOPK) cb = (EXP2F(rv) - 1.f) / LOG2F((float)(rnk + 2));
    }
    // dual interleaved wave reduce (dcg, bdcg)
#pragma unroll
    for (int mm = 32; mm >= 1; mm >>= 1) {
      cd += __shfl_xor(cd, mm, 64);
      cb += __shfl_xor(cb, mm, 64);
    }
    if (ln == 0) { sh_w1[wv] = cd; sh_w2[wv] = cb; }
    __syncthreads();
    if (t == 0) {
      float adcg = 0.f;
#pragma unroll
      for (int r = 0; r < TOPK; r++)
        adcg += (EXP2F(sh_row[r]) - 1.f) / LOG2F((float)(r + 2));
      float dcg = 0.f, bdcg = 0.f;
#pragma unroll
      for (int w2 = 0; w2 < 8; w2++) { dcg += sh_w1[w2]; bdcg += sh_w2[w2]; }
      out[u] = adcg / bdcg;
      out[U_CNT + u] = dcg / bdcg;
    }
  } else {
    // ===================== Diversity path =====================
    {  // approx_rank col pass, banded, weights folded (sh_lw)
      const float qsr = sh_Qs[PAD + t];
      const float c0 = sh_Uu[PAD + t];
      const float4* l4 = (const float4*)(sh_lw + PAD + base);
      float acc0 = 0.f, acc1 = 0.f;
      float v = 511.f - 2.f * (float)base;
#pragma unroll 4
      for (int c = 0; c < NCH; c++) {
        float4 r = l4[c];
        acc0 += EXP2F(fmaf(v, qsr, c0) + r.x); v -= 2.f;
        acc1 += EXP2F(fmaf(v, qsr, c0) + r.y); v -= 2.f;
        acc0 += EXP2F(fmaf(v, qsr, c0) + r.z); v -= 2.f;
        acc1 += EXP2F(fmaf(v, qsr, c0) + r.w); v -= 2.f;
      }
      float ar = acc0 + acc1;
      float arj_s = 1.f / (1.f + EXP2F((502.f - ar) * LOG2E));  // sigmoid
      int o = sh_pos[t];
      sh_aux[o] = arj_s;                  // scatter to orig item index
      sh_rr[o] = (t < TOPK) ? 1.f : 0.f;  // desc rank < 10 -> top-10
    }
    float inv = 1.f / fmaxf(sqrtf(ssq), 1e-8f);  // orig item t (early ssq)
    sh_inv[t] = inv;
    float om = 1.f - ssq * inv * inv;  // 1 - ||n||^2 for ORIG item t
    __syncthreads();
    float arj = sh_aux[t], rrj = sh_rr[t];
    float r1 = arj, r2 = arj * arj, r3 = arj * arj * om, r4v = rrj,
          r5v = rrj * om;
#pragma unroll
    for (int mm = 32; mm >= 1; mm >>= 1) {
      r1 += __shfl_xor(r1, mm, 64);
      r2 += __shfl_xor(r2, mm, 64);
      r3 += __shfl_xor(r3, mm, 64);
      r4v += __shfl_xor(r4v, mm, 64);
      r5v += __shfl_xor(r5v, mm, 64);
    }
    if (ln == 0) {
      sh_w1[wv] = r1; sh_w2[wv] = r2; sh_w3[wv] = r3;
      sh_w4[wv] = r4v; sh_w5[wv] = r5v;
    }
    // V = sum_j a_j * n_j (64-dim): wave wv handles 64 j's, lane = feature
    const float* bu = batch + (size_t)u * N * F_STRIDE;
    float va = 0.f, vr = 0.f;
#pragma unroll 4
    for (int jj = 0; jj < 64; jj++) {
      int j2 = (wv << 6) + jj;
      float x = bu[(size_t)j2 * F_STRIDE + ln] * sh_inv[j2];
      va = fmaf(sh_aux[j2], x, va);
      vr = fmaf(sh_rr[j2], x, vr);
    }
    sh_pA[t] = va;
    sh_pB[t] = vr;
    __syncthreads();
    float qa = 0.f, qr = 0.f;
    if (t < 64) {
      float VA = 0.f, VR = 0.f;
#pragma unroll
      for (int c2 = 0; c2 < 8; c2++) {
        VA += sh_pA[c2 * 64 + t];
        VR += sh_pB[c2 * 64 + t];
      }
      qa = VA * VA;
      qr = VR * VR;
    }
#pragma unroll
    for (int mm = 32; mm >= 1; mm >>= 1) {
      qa += __shfl_xor(qa, mm, 64);
      qr += __shfl_xor(qr, mm, 64);
    }
    if (t == 0) {  // qa/qr complete in wave 0; sh_w* visible since last bar
      float S1a = 0.f, S2a = 0.f, DA = 0.f, S1r = 0.f, DR = 0.f;
#pragma unroll
      for (int w2 = 0; w2 < 8; w2++) {
        S1a += sh_w1[w2]; S2a += sh_w2[w2]; DA += sh_w3[w2];
        S1r += sh_w4[w2]; DR += sh_w5[w2];
      }
      // sum_{i<j} a_i a_j (1 - n_i.n_j) = 0.5*(S1^2 - ||V||^2 - diag)
      float numA = 0.5f * (S1a * S1a - qa - DA);
      float denA = 0.5f * (S1a * S1a - S2a);
      out[2 * U_CNT + u] = numA / denA;
      float numR = 0.5f * (S1r * S1r - qr - DR);
      float denR = 0.5f * (S1r * S1r - S1r);
      out[3 * U_CNT + u] = numR / denR;
    }
  }
}

extern "C" void kernel_launch(void* const* d_in, const int* in_sizes, int n_in,
                              void* d_out, int out_size, void* d_ws,
                              size_t ws_size, hipStream_t stream) {
  (void)in_sizes; (void)n_in; (void)d_ws; (void)ws_size; (void)out_size;
  const float* batch = (const float*)d_in[0];
  const float* sdiv = (const float*)d_in[1];
  const float* sndcg = (const float*)d_in[2];
  const float* rel = (const float*)d_in[3];
  float* out = (float*)d_out;
  loss_kernel<<<dim3(U_CNT * 2), dim3(N), 0, stream>>>(batch, sdiv, sndcg, rel,
                                                       out);
}

// Round 8
// 56.633 us; speedup vs baseline: 2.9090x; 1.0078x over previous
//
#include <hip/hip_runtime.h>

#define N 512
#define U_CNT 128
#define F_STRIDE 80
#define TOPK 10
#define W 48                  // half band width (sorted space)
#define PAD 64
#define BSZ (PAD + N + PAD)   // 640
#define NCH ((2 * W + 4) / 4) // 25 band float4 chunks
#define BAND (2 * W + 4)      // 100
// log2(e)/tau with tau = 0.1
#define L2T 14.426950408889634f
#define LOG2E 1.4426950408889634f
#define NEGBIG -1.0e30f

#if defined(__has_builtin)
#if __has_builtin(__builtin_amdgcn_exp2f)
#define EXP2F(x) __builtin_amdgcn_exp2f(x)
#endif
#if __has_builtin(__builtin_amdgcn_logf)
#define LOG2F(x) __builtin_amdgcn_logf(x)
#endif
#endif
#ifndef EXP2F
#define EXP2F(x) exp2f(x)
#endif
#ifndef LOG2F
#define LOG2F(x) log2f(x)
#endif

// monotone sortable key: ascending key order == descending value order,
// ties broken by smaller idx first (stable, matches jnp.argsort on -score)
__device__ __forceinline__ unsigned long long sortkey(float x, int idx) {
  unsigned int bb = __float_as_uint(x);
  bb ^= (unsigned int)((int)bb >> 31) | 0x80000000u;
  return ((unsigned long long)(~bb) << 10) | (unsigned long long)idx;
}

// One block per (user, which), 256 threads (4 waves) -> 512 blocks total =
// 2 independent blocks/CU (barrier stalls of one absorbed by the other).
// Thread t owns sorted rows/cols t and t+256 (dual streams, 2x ILP).
// Sinkhorn state in rank-sorted space: Qs, Uu (cols), Rl (rows), padded with
// -1e30 so out-of-band elements give exp2() = 0 (band truncation beyond W
// underflows in f32).
__global__ __launch_bounds__(256) void loss_kernel(
    const float* __restrict__ batch, const float* __restrict__ sdiv,
    const float* __restrict__ sndcg, const float* __restrict__ rel,
    float* __restrict__ out) {
  __shared__ __align__(16) unsigned long long sh_key[N];
  __shared__ __align__(16) float sh_sv[N];    // sorted raw score
  __shared__ __align__(16) int sh_pos[N];     // rank -> orig index
  __shared__ __align__(16) float sh_Qs[BSZ];  // sorted qs (pad 0)
  __shared__ __align__(16) float sh_Uu[BSZ];  // col log-factor (pad -1e30)
  __shared__ __align__(16) float sh_Rl[BSZ];  // row log-factor (pad -1e30)
  __shared__ __align__(16) float sh_lw[BSZ];  // Rl + log2(w) (pad -1e30)
  __shared__ __align__(16) float sh_relS[N];  // rel sorted by score rank
  __shared__ __align__(16) float sh_aux[N];   // rel orig (ndcg) | arj orig (div)
  __shared__ __align__(16) float sh_inv[N];
  __shared__ __align__(16) float sh_rr[N];
  __shared__ __align__(16) float sh_pA[256];
  __shared__ __align__(16) float sh_pB[256];
  __shared__ float sh_red[8];
  __shared__ float sh_w1[4], sh_w2[4], sh_w3[4], sh_w4[4], sh_w5[4];
  __shared__ float sh_row[TOPK];

  const int b = blockIdx.x;
  const int u = b >> 1;
  const int which = b & 1;
  const int t = threadIdx.x;   // 0..255
  const int i1 = t + 256;
  const int wv = t >> 6;       // 0..3
  const int ln = t & 63;

  // pad init (exponent sentinels)
  if (t < PAD) {
    sh_Qs[t] = 0.f; sh_Uu[t] = NEGBIG; sh_Rl[t] = NEGBIG; sh_lw[t] = NEGBIG;
  } else if (t < 2 * PAD) {
    int p = N + t;  // PAD + N + (t - PAD)
    sh_Qs[p] = 0.f; sh_Uu[p] = NEGBIG; sh_Rl[p] = NEGBIG; sh_lw[p] = NEGBIG;
  }

  const float* score = (which ? sdiv : sndcg) + (size_t)u * N;
  const float sj0 = score[t];
  const float sj1 = score[i1];
  sh_key[t] = sortkey(sj0, t);
  sh_key[i1] = sortkey(sj1, i1);
  if (!which) {
    sh_aux[t] = rel[(size_t)u * N + t];
    sh_aux[i1] = rel[(size_t)u * N + i1];
  }
  float ssq0 = 0.f, ssq1 = 0.f;
  if (which) {  // early item-norm: global latency hides under rank pass
    const float4* f0 = (const float4*)(batch + (size_t)(u * N + t) * F_STRIDE);
    const float4* f1 = (const float4*)(batch + (size_t)(u * N + i1) * F_STRIDE);
#pragma unroll
    for (int f4 = 0; f4 < 16; f4++) {
      float4 p = f0[f4], q = f1[f4];
      ssq0 = fmaf(p.x, p.x, ssq0); ssq0 = fmaf(p.y, p.y, ssq0);
      ssq0 = fmaf(p.z, p.z, ssq0); ssq0 = fmaf(p.w, p.w, ssq0);
      ssq1 = fmaf(q.x, q.x, ssq1); ssq1 = fmaf(q.y, q.y, ssq1);
      ssq1 = fmaf(q.z, q.z, ssq1); ssq1 = fmaf(q.w, q.w, ssq1);
    }
  }
  __syncthreads();

  // ---- rank pass: stable descending rank via u64 key counting (dual) ----
  {
    const unsigned long long k0 = sh_key[t], k1 = sh_key[i1];
    const ulonglong2* k2 = (const ulonglong2*)sh_key;
    int r0 = 0, r1 = 0;
#pragma unroll 8
    for (int i = 0; i < N / 2; i++) {
      ulonglong2 kk = k2[i];
      r0 += (kk.x < k0); r0 += (kk.y < k0);
      r1 += (kk.x < k1); r1 += (kk.y < k1);
    }
    sh_sv[r0] = sj0; sh_pos[r0] = t;
    sh_sv[r1] = sj1; sh_pos[r1] = i1;
  }
  __syncthreads();

  // ---- sorted-space setup: Qs, relS, asum via dual prefix scan ----
  const float sv0 = sh_sv[t], sv1 = sh_sv[i1];
  sh_Qs[PAD + t] = sv0 * L2T;
  sh_Qs[PAD + i1] = sv1 * L2T;
  if (!which) {
    sh_relS[t] = sh_aux[sh_pos[t]];
    sh_relS[i1] = sh_aux[sh_pos[i1]];
  }
  {
    float ps0 = sv0, ps1 = sv1;  // inclusive wave scans
#pragma unroll
    for (int m = 1; m <= 32; m <<= 1) {
      float o0 = __shfl_up(ps0, m, 64);
      float o1 = __shfl_up(ps1, m, 64);
      if (ln >= m) { ps0 += o0; ps1 += o1; }
    }
    if (ln == 63) { sh_red[wv] = ps0; sh_red[4 + wv] = ps1; }
    __syncthreads();
    float off0 = 0.f, T0 = 0.f, off1 = 0.f, T1 = 0.f;
#pragma unroll
    for (int w2 = 0; w2 < 4; w2++) {
      float a = sh_red[w2], c = sh_red[4 + w2];
      if (w2 < wv) { off0 += a; off1 += c; }
      T0 += a; T1 += c;
    }
    float S0 = ps0 + off0;            // inclusive prefix at sorted pos t
    float S1 = T0 + ps1 + off1;       // at pos t+256
    float T = T0 + T1;
    float as0 = 2.f * S0 - T + (float)(N - 2 - 2 * t) * sv0;
    float as1 = 2.f * S1 - T + (float)(N - 2 - 2 * i1) * sv1;
    sh_Uu[PAD + t] = -as0 * L2T;
    sh_Uu[PAD + i1] = -as1 * L2T;
  }
  __syncthreads();

  // band geometry (float4-aligned, covers [pos-W, pos+W])
  const int base0 = (t & ~3) - W;     // PAD+base0 >= 16, multiple of 4
  const int base1 = base0 + 256;
  const float vi0 = 511.f - 2.f * (float)t;
  const float vi1 = 511.f - 2.f * (float)i1;

  // ---- initial row softmax: exact peak at col=pos (unimodal), banded Z ----
  {
    float m0, m1;
    {
      float e0 = fmaf(vi0, sh_Qs[PAD + t - 1], sh_Uu[PAD + t - 1]);
      float e1 = fmaf(vi0, sh_Qs[PAD + t], sh_Uu[PAD + t]);
      float e2 = fmaf(vi0, sh_Qs[PAD + t + 1], sh_Uu[PAD + t + 1]);
      m0 = fmaxf(e1, fmaxf(e0, e2));
      float g0 = fmaf(vi1, sh_Qs[PAD + i1 - 1], sh_Uu[PAD + i1 - 1]);
      float g1 = fmaf(vi1, sh_Qs[PAD + i1], sh_Uu[PAD + i1]);
      float g2 = fmaf(vi1, sh_Qs[PAD + i1 + 1], sh_Uu[PAD + i1 + 1]);
      m1 = fmaxf(g1, fmaxf(g0, g2));
    }
    const float4* q40 = (const float4*)(sh_Qs + PAD + base0);
    const float4* u40 = (const float4*)(sh_Uu + PAD + base0);
    const float4* q41 = (const float4*)(sh_Qs + PAD + base1);
    const float4* u41 = (const float4*)(sh_Uu + PAD + base1);
    float Z0 = 0.f, Z1 = 0.f;
#pragma unroll 5
    for (int c = 0; c < NCH; c++) {
      float4 a = q40[c], cc = u40[c];
      float4 d = q41[c], ee = u41[c];
      Z0 += EXP2F(fmaf(vi0, a.x, cc.x) - m0);
      Z1 += EXP2F(fmaf(vi1, d.x, ee.x) - m1);
      Z0 += EXP2F(fmaf(vi0, a.y, cc.y) - m0);
      Z1 += EXP2F(fmaf(vi1, d.y, ee.y) - m1);
      Z0 += EXP2F(fmaf(vi0, a.z, cc.z) - m0);
      Z1 += EXP2F(fmaf(vi1, d.z, ee.z) - m1);
      Z0 += EXP2F(fmaf(vi0, a.w, cc.w) - m0);
      Z1 += EXP2F(fmaf(vi1, d.w, ee.w) - m1);
    }
    sh_Rl[PAD + t] = -m0 - LOG2F(Z0);
    sh_Rl[PAD + i1] = -m1 - LOG2F(Z1);
  }
  __syncthreads();

  // ---- 5 Sinkhorn iterations, banded (col normalize, then row) ----
#pragma unroll 1
  for (int it = 0; it < 5; it++) {
    {  // col pass: columns t, i1; rows in band; u folded -> true col sums
      const float qs0 = sh_Qs[PAD + t], c00 = sh_Uu[PAD + t];
      const float qs1 = sh_Qs[PAD + i1], c01 = sh_Uu[PAD + i1];
      const float4* r40 = (const float4*)(sh_Rl + PAD + base0);
      const float4* r41 = (const float4*)(sh_Rl + PAD + base1);
      float a0 = 0.f, a1 = 0.f, a2 = 0.f, a3 = 0.f;
      float v0 = 511.f - 2.f * (float)base0;
      float v1 = 511.f - 2.f * (float)base1;
#pragma unroll 5
      for (int c = 0; c < NCH; c++) {
        float4 ra = r40[c], rb = r41[c];
        a0 += EXP2F(fmaf(v0, qs0, c00) + ra.x); v0 -= 2.f;
        a1 += EXP2F(fmaf(v1, qs1, c01) + rb.x); v1 -= 2.f;
        a2 += EXP2F(fmaf(v0, qs0, c00) + ra.y); v0 -= 2.f;
        a3 += EXP2F(fmaf(v1, qs1, c01) + rb.y); v1 -= 2.f;
        a0 += EXP2F(fmaf(v0, qs0, c00) + ra.z); v0 -= 2.f;
        a1 += EXP2F(fmaf(v1, qs1, c01) + rb.z); v1 -= 2.f;
        a2 += EXP2F(fmaf(v0, qs0, c00) + ra.w); v0 -= 2.f;
        a3 += EXP2F(fmaf(v1, qs1, c01) + rb.w); v1 -= 2.f;
      }
      sh_Uu[PAD + t] = c00 - LOG2F(fmaxf(a0 + a2, 1e-10f));
      sh_Uu[PAD + i1] = c01 - LOG2F(fmaxf(a1 + a3, 1e-10f));
    }
    __syncthreads();
    {  // row pass: rows t, i1; cols in band
      const float rl0 = sh_Rl[PAD + t];
      const float rl1 = sh_Rl[PAD + i1];
      const float4* q40 = (const float4*)(sh_Qs + PAD + base0);
      const float4* u40 = (const float4*)(sh_Uu + PAD + base0);
      const float4* q41 = (const float4*)(sh_Qs + PAD + base1);
      const float4* u41 = (const float4*)(sh_Uu + PAD + base1);
      float a0 = 0.f, a1 = 0.f, a2 = 0.f, a3 = 0.f;
#pragma unroll 5
      for (int c = 0; c < NCH; c++) {
        float4 a = q40[c], cc = u40[c];
        float4 d = q41[c], ee = u41[c];
        a0 += EXP2F(fmaf(vi0, a.x, cc.x) + rl0);
        a1 += EXP2F(fmaf(vi1, d.x, ee.x) + rl1);
        a2 += EXP2F(fmaf(vi0, a.y, cc.y) + rl0);
        a3 += EXP2F(fmaf(vi1, d.y, ee.y) + rl1);
        a0 += EXP2F(fmaf(vi0, a.z, cc.z) + rl0);
        a1 += EXP2F(fmaf(vi1, d.z, ee.z) + rl1);
        a2 += EXP2F(fmaf(vi0, a.w, cc.w) + rl0);
        a3 += EXP2F(fmaf(vi1, d.w, ee.w) + rl1);
      }
      float nr0 = rl0 - LOG2F(fmaxf(a0 + a2, 1e-10f));
      float nr1 = rl1 - LOG2F(fmaxf(a1 + a3, 1e-10f));
      sh_Rl[PAD + t] = nr0;
      sh_Rl[PAD + i1] = nr1;
      if (which && it == 4) {  // fold lw for div's approx_rank pass
        sh_lw[PAD + t] = nr0 + LOG2F((float)(N - t));
        sh_lw[PAD + i1] = nr1 + LOG2F((float)(N - i1));
      }
    }
    __syncthreads();
  }

  if (which == 0) {
    // ===================== NDCG path =====================
    // wave-per-row approx_rel: wave wv owns p-rows wv, wv+4, wv+8 (no bar)
#pragma unroll
    for (int r = wv; r < TOPK; r += 4) {
      const float cv = 511.f - 2.f * (float)r;
      const float rl = sh_Rl[PAD + r];
      const int rbase = (r & ~3) - W;
      float srel = 0.f;
#pragma unroll
      for (int k = 0; k < 2; k++) {
        int e = ln + 64 * k;
        if (e < BAND) {
          int j = rbase + e;
          float ex = fmaf(cv, sh_Qs[PAD + j], sh_Uu[PAD + j]) + rl;
          float rv2 = ((unsigned)j < N) ? sh_relS[j] : 0.f;
          srel = fmaf(EXP2F(ex), rv2, srel);
        }
      }
#pragma unroll
      for (int mm = 32; mm >= 1; mm >>= 1) srel += __shfl_xor(srel, mm, 64);
      if (ln == 0) sh_row[r] = srel;
    }
    // dcg contrib: sorted position t holds the item at descending rank t
    float cd = (t < TOPK)
        ? (EXP2F(sh_relS[t]) - 1.f) / LOG2F((float)(t + 2)) : 0.f;
    // bdcg: rel ranks via u64 keys (dual, reuse sh_key)
    const float rv0 = sh_aux[t], rv1 = sh_aux[i1];
    sh_key[t] = sortkey(rv0, t);
    sh_key[i1] = sortkey(rv1, i1);
    __syncthreads();
    float cb = 0.f;
    {
      const unsigned long long k0 = sh_key[t], k1 = sh_key[i1];
      const ulonglong2* k2 = (const ulonglong2*)sh_key;
      int r0 = 0, r1 = 0;
#pragma unroll 8
      for (int i = 0; i < N / 2; i++) {
        ulonglong2 kk = k2[i];
        r0 += (kk.x < k0); r0 += (kk.y < k0);
        r1 += (kk.x < k1); r1 += (kk.y < k1);
      }
      if (r0 < TOPK) cb += (EXP2F(rv0) - 1.f) / LOG2F((float)(r0 + 2));
      if (r1 < TOPK) cb += (EXP2F(rv1) - 1.f) / LOG2F((float)(r1 + 2));
    }
    // dual interleaved wave reduce (dcg, bdcg)
#pragma unroll
    for (int mm = 32; mm >= 1; mm >>= 1) {
      cd += __shfl_xor(cd, mm, 64);
      cb += __shfl_xor(cb, mm, 64);
    }
    if (ln == 0) { sh_w1[wv] = cd; sh_w2[wv] = cb; }
    __syncthreads();
    if (t == 0) {
      float adcg = 0.f;
#pragma unroll
      for (int r = 0; r < TOPK; r++)
        adcg += (EXP2F(sh_row[r]) - 1.f) / LOG2F((float)(r + 2));
      float dcg = 0.f, bdcg = 0.f;
#pragma unroll
      for (int w2 = 0; w2 < 4; w2++) { dcg += sh_w1[w2]; bdcg += sh_w2[w2]; }
      out[u] = adcg / bdcg;
      out[U_CNT + u] = dcg / bdcg;
    }
  } else {
    // ===================== Diversity path =====================
    {  // approx_rank col pass, banded, weights folded (sh_lw), dual
      const float qs0 = sh_Qs[PAD + t], c00 = sh_Uu[PAD + t];
      const float qs1 = sh_Qs[PAD + i1], c01 = sh_Uu[PAD + i1];
      const float4* l40 = (const float4*)(sh_lw + PAD + base0);
      const float4* l41 = (const float4*)(sh_lw + PAD + base1);
      float a0 = 0.f, a1 = 0.f, a2 = 0.f, a3 = 0.f;
      float v0 = 511.f - 2.f * (float)base0;
      float v1 = 511.f - 2.f * (float)base1;
#pragma unroll 5
      for (int c = 0; c < NCH; c++) {
        float4 ra = l40[c], rb = l41[c];
        a0 += EXP2F(fmaf(v0, qs0, c00) + ra.x); v0 -= 2.f;
        a1 += EXP2F(fmaf(v1, qs1, c01) + rb.x); v1 -= 2.f;
        a2 += EXP2F(fmaf(v0, qs0, c00) + ra.y); v0 -= 2.f;
        a3 += EXP2F(fmaf(v1, qs1, c01) + rb.y); v1 -= 2.f;
        a0 += EXP2F(fmaf(v0, qs0, c00) + ra.z); v0 -= 2.f;
        a1 += EXP2F(fmaf(v1, qs1, c01) + rb.z); v1 -= 2.f;
        a0 += EXP2F(fmaf(v0, qs0, c00) + ra.w); v0 -= 2.f;
        a1 += EXP2F(fmaf(v1, qs1, c01) + rb.w); v1 -= 2.f;
      }
      float ar0 = a0 + a2, ar1 = a1 + a3;
      float aj0 = 1.f / (1.f + EXP2F((502.f - ar0) * LOG2E));
      float aj1 = 1.f / (1.f + EXP2F((502.f - ar1) * LOG2E));
      int o0 = sh_pos[t], o1 = sh_pos[i1];
      sh_aux[o0] = aj0;                   // scatter to orig item index
      sh_aux[o1] = aj1;
      sh_rr[o0] = (t < TOPK) ? 1.f : 0.f; // desc rank < 10 -> top-10
      sh_rr[o1] = 0.f;                    // i1 >= 256 never top-10
    }
    float inv0 = 1.f / fmaxf(sqrtf(ssq0), 1e-8f);  // orig items t, i1
    float inv1 = 1.f / fmaxf(sqrtf(ssq1), 1e-8f);
    sh_inv[t] = inv0;
    sh_inv[i1] = inv1;
    float om0 = 1.f - ssq0 * inv0 * inv0;  // 1 - ||n||^2
    float om1 = 1.f - ssq1 * inv1 * inv1;
    __syncthreads();
    float aj0 = sh_aux[t], aj1 = sh_aux[i1];
    float rj0 = sh_rr[t], rj1 = sh_rr[i1];
    float r1 = aj0 + aj1;
    float r2 = aj0 * aj0 + aj1 * aj1;
    float r3 = aj0 * aj0 * om0 + aj1 * aj1 * om1;
    float r4v = rj0 + rj1;
    float r5v = rj0 * om0 + rj1 * om1;
#pragma unroll
    for (int mm = 32; mm >= 1; mm >>= 1) {
      r1 += __shfl_xor(r1, mm, 64);
      r2 += __shfl_xor(r2, mm, 64);
      r3 += __shfl_xor(r3, mm, 64);
      r4v += __shfl_xor(r4v, mm, 64);
      r5v += __shfl_xor(r5v, mm, 64);
    }
    if (ln == 0) {
      sh_w1[wv] = r1; sh_w2[wv] = r2; sh_w3[wv] = r3;
      sh_w4[wv] = r4v; sh_w5[wv] = r5v;
    }
    // V = sum_j a_j * n_j (64-dim): wave wv handles 128 j's, lane = feature
    const float* bu = batch + (size_t)u * N * F_STRIDE;
    float va = 0.f, vr = 0.f;
#pragma unroll 4
    for (int jj = 0; jj < 128; jj++) {
      int j2 = (wv << 7) + jj;
      float x = bu[(size_t)j2 * F_STRIDE + ln] * sh_inv[j2];
      va = fmaf(sh_aux[j2], x, va);
      vr = fmaf(sh_rr[j2], x, vr);
    }
    sh_pA[t] = va;
    sh_pB[t] = vr;
    __syncthreads();
    float qa = 0.f, qr = 0.f;
    if (t < 64) {
      float VA = 0.f, VR = 0.f;
#pragma unroll
      for (int c2 = 0; c2 < 4; c2++) {
        VA += sh_pA[c2 * 64 + t];
        VR += sh_pB[c2 * 64 + t];
      }
      qa = VA * VA;
      qr = VR * VR;
    }
#pragma unroll
    for (int mm = 32; mm >= 1; mm >>= 1) {
      qa += __shfl_xor(qa, mm, 64);
      qr += __shfl_xor(qr, mm, 64);
    }
    if (t == 0) {  // qa/qr complete in wave 0; sh_w* visible since last bar
      float S1a = 0.f, S2a = 0.f, DA = 0.f, S1r = 0.f, DR = 0.f;
#pragma unroll
      for (int w2 = 0; w2 < 4; w2++) {
        S1a += sh_w1[w2]; S2a += sh_w2[w2]; DA += sh_w3[w2];
        S1r += sh_w4[w2]; DR += sh_w5[w2];
      }
      // sum_{i<j} a_i a_j (1 - n_i.n_j) = 0.5*(S1^2 - ||V||^2 - diag)
      float numA = 0.5f * (S1a * S1a - qa - DA);
      float denA = 0.5f * (S1a * S1a - S2a);
      out[2 * U_CNT + u] = numA / denA;
      float numR = 0.5f * (S1r * S1r - qr - DR);
      float denR = 0.5f * (S1r * S1r - S1r);
      out[3 * U_CNT + u] = numR / denR;
    }
  }
}

extern "C" void kernel_launch(void* const* d_in, const int* in_sizes, int n_in,
                              void* d_out, int out_size, void* d_ws,
                              size_t ws_size, hipStream_t stream) {
  (void)in_sizes; (void)n_in; (void)d_ws; (void)ws_size; (void)out_size;
  const float* batch = (const float*)d_in[0];
  const float* sdiv = (const float*)d_in[1];
  const float* sndcg = (const float*)d_in[2];
  const float* rel = (const float*)d_in[3];
  float* out = (float*)d_out;
  loss_kernel<<<dim3(U_CNT * 2), dim3(256), 0, stream>>>(batch, sdiv, sndcg,
                                                         rel, out);
}

// Round 9
// 46.125 us; speedup vs baseline: 3.5717x; 1.2278x over previous
//
#include <hip/hip_runtime.h>

#define N 512
#define U_CNT 128
#define F_STRIDE 80
#define TOPK 10
#define W 48                  // half band width (sorted space)
#define PAD 64
#define BSZ (PAD + N + PAD)   // 640
#define NCH ((2 * W + 4) / 4) // 25 band float4 chunks
#define BAND (2 * W + 4)      // 100
// log2(e)/tau with tau = 0.1
#define L2T 14.426950408889634f
#define LOG2E 1.4426950408889634f
#define NEGBIG -1.0e30f

#if defined(__has_builtin)
#if __has_builtin(__builtin_amdgcn_exp2f)
#define EXP2F(x) __builtin_amdgcn_exp2f(x)
#endif
#if __has_builtin(__builtin_amdgcn_logf)
#define LOG2F(x) __builtin_amdgcn_logf(x)
#endif
#endif
#ifndef EXP2F
#define EXP2F(x) exp2f(x)
#endif
#ifndef LOG2F
#define LOG2F(x) log2f(x)
#endif

// monotone sortable key: ascending key order == descending value order,
// ties broken by smaller idx first (stable, matches jnp.argsort on -score)
__device__ __forceinline__ unsigned long long sortkey(float x, int idx) {
  unsigned int bb = __float_as_uint(x);
  bb ^= (unsigned int)((int)bb >> 31) | 0x80000000u;
  return ((unsigned long long)(~bb) << 10) | (unsigned long long)idx;
}

// One block per (user, which), 512 threads (8 waves/CU). Thread t owns sorted
// row/col t. Sinkhorn state in rank-sorted space: Qs, Uu (cols), Rl (rows),
// padded with -1e30 so out-of-band elements give exp2() = 0 (band truncation
// beyond W underflows in f32 - verified bit-exact r5-r8).
// Qs band is preloaded into registers (pre-multiplied by vi) since it is
// constant across all 11 passes -> halves Sinkhorn LDS reads.
__global__ __launch_bounds__(512, 2) void loss_kernel(
    const float* __restrict__ batch, const float* __restrict__ sdiv,
    const float* __restrict__ sndcg, const float* __restrict__ rel,
    float* __restrict__ out) {
  __shared__ __align__(16) unsigned long long sh_key[N];
  __shared__ __align__(16) float sh_sv[N];    // sorted raw score
  __shared__ __align__(16) int sh_pos[N];     // rank -> orig index
  __shared__ __align__(16) float sh_Qs[BSZ];  // sorted qs (pad 0)
  __shared__ __align__(16) float sh_Uu[BSZ];  // col log-factor (pad -1e30)
  __shared__ __align__(16) float sh_Rl[BSZ];  // row log-factor (pad -1e30)
  __shared__ __align__(16) float sh_lw[BSZ];  // Rl + log2(w) (pad -1e30)
  __shared__ __align__(16) float sh_relS[N];  // rel sorted by score rank
  __shared__ __align__(16) float sh_aux[N];   // rel orig (ndcg) | arj orig (div)
  __shared__ __align__(16) float sh_inv[N];
  __shared__ __align__(16) float sh_rr[N];
  __shared__ __align__(16) float sh_pA[N];
  __shared__ __align__(16) float sh_pB[N];
  __shared__ float sh_red[8];
  __shared__ float sh_w1[8], sh_w2[8], sh_w3[8], sh_w4[8], sh_w5[8];
  __shared__ float sh_row[TOPK];

  const int b = blockIdx.x;
  const int u = b >> 1;
  const int which = b & 1;
  const int t = threadIdx.x;
  const int wv = t >> 6;
  const int ln = t & 63;

  // pad init (exponent sentinels)
  if (t < PAD) {
    sh_Qs[t] = 0.f; sh_Uu[t] = NEGBIG; sh_Rl[t] = NEGBIG; sh_lw[t] = NEGBIG;
  } else if (t < 2 * PAD) {
    int p = N + t;  // PAD + N + (t - PAD)
    sh_Qs[p] = 0.f; sh_Uu[p] = NEGBIG; sh_Rl[p] = NEGBIG; sh_lw[p] = NEGBIG;
  }

  const float sj = ((which ? sdiv : sndcg) + (size_t)u * N)[t];
  sh_key[t] = sortkey(sj, t);
  if (!which) sh_aux[t] = rel[(size_t)u * N + t];
  float ssq = 0.f;
  if (which) {  // early item-norm: global latency hides under rank pass
    const float4* it4 =
        (const float4*)(batch + (size_t)(u * N + t) * F_STRIDE);
#pragma unroll
    for (int f4 = 0; f4 < 16; f4++) {
      float4 p = it4[f4];
      ssq = fmaf(p.x, p.x, ssq); ssq = fmaf(p.y, p.y, ssq);
      ssq = fmaf(p.z, p.z, ssq); ssq = fmaf(p.w, p.w, ssq);
    }
  }
  __syncthreads();

  // ---- rank pass: stable descending rank via u64 key counting ----
  {
    const unsigned long long myk = sh_key[t];
    const ulonglong2* k2 = (const ulonglong2*)sh_key;
    int rnk = 0;
#pragma unroll 8
    for (int i = 0; i < N / 2; i++) {
      ulonglong2 kk = k2[i];
      rnk += (kk.x < myk);
      rnk += (kk.y < myk);
    }
    sh_sv[rnk] = sj;
    sh_pos[rnk] = t;
  }
  __syncthreads();

  // ---- sorted-space setup: Qs, relS, asum via prefix scan ----
  const float sv = sh_sv[t];
  sh_Qs[PAD + t] = sv * L2T;
  if (!which) sh_relS[t] = sh_aux[sh_pos[t]];
  {
    float ps = sv;  // inclusive wave scan
#pragma unroll
    for (int m = 1; m <= 32; m <<= 1) {
      float o = __shfl_up(ps, m, 64);
      if (ln >= m) ps += o;
    }
    if (ln == 63) sh_red[wv] = ps;
    __syncthreads();
    float off = 0.f, Tt = 0.f;
#pragma unroll
    for (int w2 = 0; w2 < 8; w2++) {
      float rv = sh_red[w2];
      if (w2 < wv) off += rv;
      Tt += rv;
    }
    float S = ps + off;  // inclusive prefix over block (desc sorted)
    float asum = 2.f * S - Tt + (float)(N - 2 - 2 * t) * sv;
    sh_Uu[PAD + t] = -asum * L2T;
  }
  __syncthreads();

  // band geometry (float4-aligned, covers [t-W, t+W])
  const int base = (t & ~3) - W;  // PAD+base >= 16, multiple of 4
  const float vi = 511.f - 2.f * (float)t;

  // ---- preload Qs band into registers, pre-multiplied by vi ----
  float4 hq[NCH];
  {
    const float4* q4 = (const float4*)(sh_Qs + PAD + base);
#pragma unroll
    for (int c = 0; c < NCH; c++) {
      float4 a = q4[c];
      hq[c].x = vi * a.x; hq[c].y = vi * a.y;
      hq[c].z = vi * a.z; hq[c].w = vi * a.w;
    }
  }

  // ---- initial row softmax: exact peak at col=t (unimodal), banded Z ----
  {
    float e0 = fmaf(vi, sh_Qs[PAD + t - 1], sh_Uu[PAD + t - 1]);
    float e1 = fmaf(vi, sh_Qs[PAD + t], sh_Uu[PAD + t]);
    float e2 = fmaf(vi, sh_Qs[PAD + t + 1], sh_Uu[PAD + t + 1]);
    float em = -fmaxf(e1, fmaxf(e0, e2));
    const float4* u4 = (const float4*)(sh_Uu + PAD + base);
    float Z = 0.f;
#pragma unroll
    for (int c = 0; c < NCH; c++) {
      float4 cc = u4[c];
      Z += EXP2F(hq[c].x + cc.x + em);
      Z += EXP2F(hq[c].y + cc.y + em);
      Z += EXP2F(hq[c].z + cc.z + em);
      Z += EXP2F(hq[c].w + cc.w + em);
    }
    sh_Rl[PAD + t] = em - LOG2F(Z);
  }
  __syncthreads();

  // ---- 5 Sinkhorn iterations, banded (col normalize, then row) ----
#pragma unroll 1
  for (int it = 0; it < 5; it++) {
    {  // col pass: column t, rows i in band; u folded -> acc = true col sum
      const float qsr = sh_Qs[PAD + t];
      const float c0 = sh_Uu[PAD + t];
      const float4* r4 = (const float4*)(sh_Rl + PAD + base);
      float acc0 = 0.f, acc1 = 0.f;
      float v = 511.f - 2.f * (float)base;
#pragma unroll
      for (int c = 0; c < NCH; c++) {
        float4 r = r4[c];
        acc0 += EXP2F(fmaf(v, qsr, c0) + r.x); v -= 2.f;
        acc1 += EXP2F(fmaf(v, qsr, c0) + r.y); v -= 2.f;
        acc0 += EXP2F(fmaf(v, qsr, c0) + r.z); v -= 2.f;
        acc1 += EXP2F(fmaf(v, qsr, c0) + r.w); v -= 2.f;
      }
      sh_Uu[PAD + t] = c0 - LOG2F(fmaxf(acc0 + acc1, 1e-10f));
    }
    __syncthreads();
    {  // row pass: row t, cols r in band (Qs from registers)
      const float rli = sh_Rl[PAD + t];
      const float4* u4 = (const float4*)(sh_Uu + PAD + base);
      float acc = 0.f;
#pragma unroll
      for (int c = 0; c < NCH; c++) {
        float4 cc = u4[c];
        acc += EXP2F(hq[c].x + cc.x + rli);
        acc += EXP2F(hq[c].y + cc.y + rli);
        acc += EXP2F(hq[c].z + cc.z + rli);
        acc += EXP2F(hq[c].w + cc.w + rli);
      }
      float nr = rli - LOG2F(fmaxf(acc, 1e-10f));
      sh_Rl[PAD + t] = nr;
      if (which && it == 4)  // fold lw for div's approx_rank pass
        sh_lw[PAD + t] = nr + LOG2F((float)(N - t));
    }
    __syncthreads();
  }

  if (which == 0) {
    // ===================== NDCG path =====================
    // wave-per-row approx_rel: wave wv owns p-rows wv, wv+8 (bands), no bar
#pragma unroll
    for (int r = wv; r < TOPK; r += 8) {
      const float cv = 511.f - 2.f * (float)r;
      const float rl = sh_Rl[PAD + r];
      const int rbase = (r & ~3) - W;
      float srel = 0.f;
#pragma unroll
      for (int k = 0; k < 2; k++) {
        int e = ln + 64 * k;
        if (e < BAND) {
          int j = rbase + e;
          float ex = fmaf(cv, sh_Qs[PAD + j], sh_Uu[PAD + j]) + rl;
          float rv2 = ((unsigned)j < N) ? sh_relS[j] : 0.f;
          srel = fmaf(EXP2F(ex), rv2, srel);
        }
      }
#pragma unroll
      for (int mm = 32; mm >= 1; mm >>= 1) srel += __shfl_xor(srel, mm, 64);
      if (ln == 0) sh_row[r] = srel;
    }
    // dcg contrib: sorted position t holds the item at descending rank t
    float cd = (t < TOPK)
        ? (EXP2F(sh_relS[t]) - 1.f) / LOG2F((float)(t + 2)) : 0.f;
    // bdcg: rel rank via u64 keys (reuse sh_key)
    const float rv = sh_aux[t];
    sh_key[t] = sortkey(rv, t);
    __syncthreads();
    float cb = 0.f;
    {
      const unsigned long long myk = sh_key[t];
      const ulonglong2* k2 = (const ulonglong2*)sh_key;
      int rnk = 0;
#pragma unroll 8
      for (int i = 0; i < N / 2; i++) {
        ulonglong2 kk = k2[i];
        rnk += (kk.x < myk);
        rnk += (kk.y < myk);
      }
      if (rnk < TOPK) cb = (EXP2F(rv) - 1.f) / LOG2F((float)(rnk + 2));
    }
    // dual interleaved wave reduce (dcg, bdcg)
#pragma unroll
    for (int mm = 32; mm >= 1; mm >>= 1) {
      cd += __shfl_xor(cd, mm, 64);
      cb += __shfl_xor(cb, mm, 64);
    }
    if (ln == 0) { sh_w1[wv] = cd; sh_w2[wv] = cb; }
    __syncthreads();
    if (t == 0) {
      float adcg = 0.f;
#pragma unroll
      for (int r = 0; r < TOPK; r++)
        adcg += (EXP2F(sh_row[r]) - 1.f) / LOG2F((float)(r + 2));
      float dcg = 0.f, bdcg = 0.f;
#pragma unroll
      for (int w2 = 0; w2 < 8; w2++) { dcg += sh_w1[w2]; bdcg += sh_w2[w2]; }
      out[u] = adcg / bdcg;
      out[U_CNT + u] = dcg / bdcg;
    }
  } else {
    // ===================== Diversity path =====================
    {  // approx_rank col pass, banded, weights folded (sh_lw)
      const float qsr = sh_Qs[PAD + t];
      const float c0 = sh_Uu[PAD + t];
      const float4* l4 = (const float4*)(sh_lw + PAD + base);
      float acc0 = 0.f, acc1 = 0.f;
      float v = 511.f - 2.f * (float)base;
#pragma unroll
      for (int c = 0; c < NCH; c++) {
        float4 r = l4[c];
        acc0 += EXP2F(fmaf(v, qsr, c0) + r.x); v -= 2.f;
        acc1 += EXP2F(fmaf(v, qsr, c0) + r.y); v -= 2.f;
        acc0 += EXP2F(fmaf(v, qsr, c0) + r.z); v -= 2.f;
        acc1 += EXP2F(fmaf(v, qsr, c0) + r.w); v -= 2.f;
      }
      float ar = acc0 + acc1;
      float arj_s = 1.f / (1.f + EXP2F((502.f - ar) * LOG2E));  // sigmoid
      int o = sh_pos[t];
      sh_aux[o] = arj_s;                  // scatter to orig item index
      sh_rr[o] = (t < TOPK) ? 1.f : 0.f;  // desc rank < 10 -> top-10
    }
    float inv = 1.f / fmaxf(sqrtf(ssq), 1e-8f);  // orig item t (early ssq)
    sh_inv[t] = inv;
    float om = 1.f - ssq * inv * inv;  // 1 - ||n||^2 for ORIG item t
    __syncthreads();
    float arj = sh_aux[t], rrj = sh_rr[t];
    float r1 = arj, r2 = arj * arj, r3 = arj * arj * om, r4v = rrj,
          r5v = rrj * om;
#pragma unroll
    for (int mm = 32; mm >= 1; mm >>= 1) {
      r1 += __shfl_xor(r1, mm, 64);
      r2 += __shfl_xor(r2, mm, 64);
      r3 += __shfl_xor(r3, mm, 64);
      r4v += __shfl_xor(r4v, mm, 64);
      r5v += __shfl_xor(r5v, mm, 64);
    }
    if (ln == 0) {
      sh_w1[wv] = r1; sh_w2[wv] = r2; sh_w3[wv] = r3;
      sh_w4[wv] = r4v; sh_w5[wv] = r5v;
    }
    // V = sum_j a_j * n_j (64-dim): wave wv handles 64 j's, lane = feature
    const float* bu = batch + (size_t)u * N * F_STRIDE;
    float va = 0.f, vr = 0.f;
#pragma unroll 4
    for (int jj = 0; jj < 64; jj++) {
      int j2 = (wv << 6) + jj;
      float x = bu[(size_t)j2 * F_STRIDE + ln] * sh_inv[j2];
      va = fmaf(sh_aux[j2], x, va);
      vr = fmaf(sh_rr[j2], x, vr);
    }
    sh_pA[t] = va;
    sh_pB[t] = vr;
    __syncthreads();
    float qa = 0.f, qr = 0.f;
    if (t < 64) {
      float VA = 0.f, VR = 0.f;
#pragma unroll
      for (int c2 = 0; c2 < 8; c2++) {
        VA += sh_pA[c2 * 64 + t];
        VR += sh_pB[c2 * 64 + t];
      }
      qa = VA * VA;
      qr = VR * VR;
    }
#pragma unroll
    for (int mm = 32; mm >= 1; mm >>= 1) {
      qa += __shfl_xor(qa, mm, 64);
      qr += __shfl_xor(qr, mm, 64);
    }
    if (t == 0) {  // qa/qr complete in wave 0; sh_w* visible since last bar
      float S1a = 0.f, S2a = 0.f, DA = 0.f, S1r = 0.f, DR = 0.f;
#pragma unroll
      for (int w2 = 0; w2 < 8; w2++) {
        S1a += sh_w1[w2]; S2a += sh_w2[w2]; DA += sh_w3[w2];
        S1r += sh_w4[w2]; DR += sh_w5[w2];
      }
      // sum_{i<j} a_i a_j (1 - n_i.n_j) = 0.5*(S1^2 - ||V||^2 - diag)
      float numA = 0.5f * (S1a * S1a - qa - DA);
      float denA = 0.5f * (S1a * S1a - S2a);
      out[2 * U_CNT + u] = numA / denA;
      float numR = 0.5f * (S1r * S1r - qr - DR);
      float denR = 0.5f * (S1r * S1r - S1r);
      out[3 * U_CNT + u] = numR / denR;
    }
  }
}

extern "C" void kernel_launch(void* const* d_in, const int* in_sizes, int n_in,
                              void* d_out, int out_size, void* d_ws,
                              size_t ws_size, hipStream_t stream) {
  (void)in_sizes; (void)n_in; (void)d_ws; (void)ws_size; (void)out_size;
  const float* batch = (const float*)d_in[0];
  const float* sdiv = (const float*)d_in[1];
  const float* sndcg = (const float*)d_in[2];
  const float* rel = (const float*)d_in[3];
  float* out = (float*)d_out;
  loss_kernel<<<dim3(U_CNT * 2), dim3(N), 0, stream>>>(batch, sdiv, sndcg, rel,
                                                       out);
}